// Round 1
// baseline (1616.689 us; speedup 1.0000x reference)
//
#include <hip/hip_runtime.h>
#include <hip/hip_bf16.h>
#include <math.h>

// Problem constants (from reference setup_inputs)
#define NNODES 100000
#define INIT_F 100
#define GC1_F  150
#define D_F    200
#define CCH    200
#define BB     128
#define NA_    8
#define EDG    500000
#define NCL    16

// ---------------- CSR build ----------------

__global__ void count_deg_k(const int* __restrict__ ei, int* __restrict__ deg, int E){
  int e = blockIdx.x*256 + threadIdx.x;
  if (e >= E) return;
  atomicAdd(&deg[ei[e]], 1);
  atomicAdd(&deg[ei[E+e]], 1);
}

__global__ void scan_block_k(const int* __restrict__ deg, int* __restrict__ incl,
                             int* __restrict__ bsum, int n){
  __shared__ int s[256];
  int t = threadIdx.x;
  int i = blockIdx.x*256 + t;
  int v = (i < n) ? deg[i] : 0;
  s[t] = v; __syncthreads();
  for (int off = 1; off < 256; off <<= 1){
    int x = (t >= off) ? s[t-off] : 0;
    __syncthreads();
    s[t] += x; __syncthreads();
  }
  if (i < n) incl[i] = s[t];
  if (t == 255) bsum[blockIdx.x] = s[255];
}

__global__ void scan_tot_k(const int* __restrict__ bsum, int* __restrict__ boff, int nb){
  __shared__ int s[512];
  int t = threadIdx.x;
  s[t] = (t < nb) ? bsum[t] : 0; __syncthreads();
  for (int off = 1; off < 512; off <<= 1){
    int x = (t >= off) ? s[t-off] : 0;
    __syncthreads();
    s[t] += x; __syncthreads();
  }
  if (t < nb) boff[t] = s[t] - bsum[t];   // exclusive block offset
}

__global__ void csr_fin_k(const int* __restrict__ incl, const int* __restrict__ deg,
                          const int* __restrict__ boff, int* __restrict__ rowptr,
                          int* __restrict__ cursor, int n, int total){
  int i = blockIdx.x*256 + threadIdx.x;
  if (i < n){
    int ex = incl[i] - deg[i] + boff[i >> 8];
    rowptr[i] = ex; cursor[i] = ex;
  }
  if (i == 0) rowptr[n] = total;
}

__global__ void fill_k(const int* __restrict__ ei, const int* __restrict__ erel,
                       int* __restrict__ cursor, int* __restrict__ adj,
                       int* __restrict__ arel, int E){
  int e = blockIdx.x*256 + threadIdx.x;
  if (e >= E) return;
  int r = ei[e], c = ei[E+e], rl = erel[e];
  int p = atomicAdd(&cursor[r], 1); adj[p] = c; arel[p] = rl;
  int q = atomicAdd(&cursor[c], 1); adj[q] = r; arel[q] = rl;
}

// ---------------- GCN gather (fuses +bias, bn, tanh) ----------------
// out[v][f] = tanh( (sum_j alpha[rel_j]*sup[u_j][f] + gb[f]) * (bng[f]*inv) + bnb[f] )

__global__ void gcn_gather_k(const float* __restrict__ sup, const int* __restrict__ rowptr,
                             const int* __restrict__ adj, const int* __restrict__ arel,
                             const float* __restrict__ alpha, const float* __restrict__ gb,
                             const float* __restrict__ bng, const float* __restrict__ bnb,
                             float* __restrict__ out, int F){
  int v = blockIdx.x;
  int f = threadIdx.x;
  int s = rowptr[v], e = rowptr[v+1];
  float acc = 0.f;
  int j = s;
  int u_n = 0; float w_n = 0.f;
  if (j < e){ u_n = adj[j]; w_n = alpha[arel[j]]; }
  while (j < e){
    int u = u_n; float w = w_n;
    ++j;
    if (j < e){ u_n = adj[j]; w_n = alpha[arel[j]]; }
    if (f < F) acc += w * sup[(long)u*F + f];
  }
  if (f < F){
    const float inv = rsqrtf(1.0f + 1e-5f);
    float x = acc + gb[f];
    x = x * (bng[f]*inv) + bnb[f];
    out[(long)v*F + f] = tanhf(x);
  }
}

// ---------------- generic 64x64 tiled fp32 GEMM ----------------
// C[M x N] = A[M x K] * B  ; BT: B stored as [N][K] (row stride ldb), else [K][N].
// ACT: 0 none, 1 leaky-relu, 2 sigmoid.
// MODE: 0 store act(dot+bias); 1 C += act(dot+bias); 2 C = act(C + dot + bias); 3 atomicAdd(C, dot)

template<int ACT, int MODE, bool BT>
__global__ __launch_bounds__(256) void gemm64(
    const float* __restrict__ A, int lda,
    const float* __restrict__ Bm, int ldb,
    float* __restrict__ Cm, int ldc,
    const float* __restrict__ bias,
    int M, int N, int K, int klen)
{
  __shared__ float As[16][68];
  __shared__ float Bs[16][68];
  int tid = threadIdx.x;
  int tm = tid >> 4, tn = tid & 15;
  int m0 = blockIdx.y*64, n0 = blockIdx.x*64;
  int k0 = blockIdx.z * klen;
  int kend = min(k0 + klen, K);
  float acc[4][4] = {};

  for (int ks = k0; ks < kend; ks += 16){
    #pragma unroll
    for (int i = 0; i < 4; i++){
      int idx = tid + 256*i;
      int m = idx & 63, k = idx >> 6;
      int gm = m0 + m, gk = ks + k;
      As[k][m] = (gm < M && gk < kend) ? A[(long)gm*lda + gk] : 0.f;
    }
    #pragma unroll
    for (int i = 0; i < 4; i++){
      int idx = tid + 256*i;
      int n = idx & 63, k = idx >> 6;
      int gn = n0 + n, gk = ks + k;
      float v = 0.f;
      if (gn < N && gk < kend)
        v = BT ? Bm[(long)gn*ldb + gk] : Bm[(long)gk*ldb + gn];
      Bs[k][n] = v;
    }
    __syncthreads();
    #pragma unroll
    for (int kk = 0; kk < 16; kk++){
      float a[4], b[4];
      #pragma unroll
      for (int i = 0; i < 4; i++) a[i] = As[kk][tm*4+i];
      #pragma unroll
      for (int i = 0; i < 4; i++) b[i] = Bs[kk][tn*4+i];
      #pragma unroll
      for (int i = 0; i < 4; i++)
        #pragma unroll
        for (int j = 0; j < 4; j++)
          acc[i][j] += a[i]*b[j];
    }
    __syncthreads();
  }

  #pragma unroll
  for (int i = 0; i < 4; i++){
    int gm = m0 + tm*4 + i; if (gm >= M) continue;
    #pragma unroll
    for (int j = 0; j < 4; j++){
      int gn = n0 + tn*4 + j; if (gn >= N) continue;
      long co = (long)gm*ldc + gn;
      float x = acc[i][j];
      if (MODE == 3){ atomicAdd(&Cm[co], x); continue; }
      if (MODE == 2) x += Cm[co];
      if (bias) x += bias[gn];
      if (ACT == 1) x = (x >= 0.f) ? x : 0.01f*x;
      else if (ACT == 2) x = 1.f/(1.f + __expf(-x));
      float r = x;
      if (MODE == 1) r = Cm[co] + x;
      Cm[co] = r;
    }
  }
}

// ---------------- small fused kernels ----------------

// s[b][0][:] = bn0(all_emb[e1[b]]), s[b][1][:] = bn0(emb_rel[rel[b]])
__global__ void build_s_k(const int* __restrict__ e1, const int* __restrict__ rel,
                          const float* __restrict__ AE, const float* __restrict__ embrel,
                          const float* __restrict__ g0, const float* __restrict__ b0,
                          float* __restrict__ s){
  int b = blockIdx.x, t = threadIdx.x;
  if (t >= D_F) return;
  const float inv = rsqrtf(1.0f + 1e-5f);
  s[(b*2+0)*D_F + t] = AE[(long)e1[b]*D_F + t] * (g0[0]*inv) + b0[0];
  s[(b*2+1)*D_F + t] = embrel[(long)rel[b]*D_F + t] * (g0[1]*inv) + b0[1];
}

// conv1d(K=5, pad=2, 2 in-ch) + bias + bn1 + relu
__global__ void conv_bn_relu_k(const float* __restrict__ s, const float* __restrict__ cw,
                               const float* __restrict__ cb, const float* __restrict__ g1,
                               const float* __restrict__ b1, float* __restrict__ out){
  __shared__ float sh[2][D_F];
  int b = blockIdx.y, c0 = blockIdx.x*8, t = threadIdx.x;
  if (t < D_F){
    sh[0][t] = s[(b*2+0)*D_F + t];
    sh[1][t] = s[(b*2+1)*D_F + t];
  }
  __syncthreads();
  if (t >= D_F) return;
  const float inv = rsqrtf(1.0f + 1e-5f);
  for (int cc = 0; cc < 8; cc++){
    int c = c0 + cc;
    float sum = cb[c];
    #pragma unroll
    for (int i = 0; i < 2; i++){
      #pragma unroll
      for (int k = 0; k < 5; k++){
        int h = t + k - 2;
        float sv = (h >= 0 && h < D_F) ? sh[i][h] : 0.f;
        sum += sv * cw[(c*2+i)*5 + k];
      }
    }
    float x = sum * (g1[c]*inv) + b1[c];
    out[((long)b*CCH + c)*D_F + t] = fmaxf(x, 0.f);
  }
}

// x2 = relu( (fcraw + fc_b) * bn2_g*inv + bn2_b )
__global__ void fc_fin_k(const float* __restrict__ raw, const float* __restrict__ fb,
                         const float* __restrict__ g, const float* __restrict__ bb,
                         float* __restrict__ x2){
  int i = blockIdx.x*256 + threadIdx.x;
  if (i >= BB*D_F) return;
  int j = i % D_F;
  const float inv = rsqrtf(1.0f + 1e-5f);
  float x = (raw[i] + fb[j]) * (g[j]*inv) + bb[j];
  x2[i] = fmaxf(x, 0.f);
}

// ssum / deep from attr gather
__global__ void feats_k(const int* __restrict__ attr, const float* __restrict__ AE,
                        float* __restrict__ ssum, float* __restrict__ deep){
  int b = blockIdx.x, t = threadIdx.x;
  if (t >= D_F) return;
  float s = 0.f, sq = 0.f;
  #pragma unroll
  for (int a = 0; a < NA_; a++){
    int id = attr[b*NA_ + a];
    float v = AE[(long)id*D_F + t];
    s += v; sq += v*v;
  }
  ssum[b*D_F + t] = s;
  deep[b*D_F + t] = 0.5f*(s*s - sq);
}

// ---------------- launch ----------------

extern "C" void kernel_launch(void* const* d_in, const int* in_sizes, int n_in,
                              void* d_out, int out_size, void* d_ws, size_t ws_size,
                              hipStream_t stream) {
  const int* e1       = (const int*)d_in[0];
  const int* rel      = (const int*)d_in[1];
  const int* attr     = (const int*)d_in[2];
  // d_in[3] = X (arange, identity gather) — unused
  const int* ei       = (const int*)d_in[4];
  const int* erel     = (const int*)d_in[5];
  const float* emb_e  = (const float*)d_in[6];
  const float* embrel = (const float*)d_in[7];
  const float* alpha1 = (const float*)d_in[8];
  const float* alpha2 = (const float*)d_in[9];
  const float* gc1_W  = (const float*)d_in[10];
  const float* gc1_b  = (const float*)d_in[11];
  const float* gc2_W  = (const float*)d_in[12];
  const float* gc2_b  = (const float*)d_in[13];
  const float* bn3_g  = (const float*)d_in[14];
  const float* bn3_b  = (const float*)d_in[15];
  const float* bn4_g  = (const float*)d_in[16];
  const float* bn4_b  = (const float*)d_in[17];
  const float* bn0_g  = (const float*)d_in[18];
  const float* bn0_b  = (const float*)d_in[19];
  const float* conv_w = (const float*)d_in[20];
  const float* conv_b = (const float*)d_in[21];
  const float* bn1_g  = (const float*)d_in[22];
  const float* bn1_b  = (const float*)d_in[23];
  const float* fc_w   = (const float*)d_in[24];
  const float* fc_b   = (const float*)d_in[25];
  const float* bn2_g  = (const float*)d_in[26];
  const float* bn2_b  = (const float*)d_in[27];
  const float* bi_w   = (const float*)d_in[28];
  const float* bi_b   = (const float*)d_in[29];
  const float* si_w   = (const float*)d_in[30];
  const float* si_b   = (const float*)d_in[31];
  const float* cs_w   = (const float*)d_in[32];
  const float* cs_b   = (const float*)d_in[33];
  const float* fc2_w  = (const float*)d_in[34];
  const float* fc2_b  = (const float*)d_in[35];

  float* pred_out = (float*)d_out;                       // 128 x 100000
  float* clus_out = (float*)d_out + (long)BB*NNODES;     // 128 x 16

  // workspace layout
  char* w = (char*)d_ws;
  size_t off = 0;
  auto alloc = [&](size_t bytes) -> void* {
    off = (off + 255) & ~(size_t)255;
    void* p = w + off;
    off += bytes;
    return p;
  };
  float* regionA = (float*)alloc((size_t)NNODES*D_F*4);  // S1, then S2, then convout
  float* regionB = (float*)alloc((size_t)NNODES*D_F*4);  // H1, then all_emb
  int* deg    = (int*)alloc((size_t)NNODES*4);
  int* incl   = (int*)alloc((size_t)NNODES*4);
  int* bsum   = (int*)alloc(512*4);
  int* boff   = (int*)alloc(512*4);
  int* rowptr = (int*)alloc((size_t)(NNODES+1)*4);
  int* cursor = (int*)alloc((size_t)NNODES*4);
  int* adj    = (int*)alloc((size_t)2*EDG*4);
  int* arel   = (int*)alloc((size_t)2*EDG*4);
  float* sbuf   = (float*)alloc((size_t)BB*2*D_F*4);
  float* x2raw  = (float*)alloc((size_t)BB*D_F*4);
  float* x2     = (float*)alloc((size_t)BB*D_F*4);
  float* ssum   = (float*)alloc((size_t)BB*D_F*4);
  float* deep   = (float*)alloc((size_t)BB*D_F*4);
  float* nfm    = (float*)alloc((size_t)BB*D_F*4);
  float* userb  = (float*)alloc((size_t)BB*D_F*4);

  float* S1 = regionA;           // N x 150
  float* S2 = regionA;           // N x 200 (S1 dead by then)
  float* convout = regionA;      // 128 x 200 x 200 (S2 dead by then)
  float* H1 = regionB;           // N x 150
  float* AE = regionB;           // N x 200 (H1 dead by then)

  const int EB = (EDG + 255)/256;           // 1954
  const int NB = (NNODES + 255)/256;        // 391

  // ---- CSR build ----
  hipMemsetAsync(deg, 0, (size_t)NNODES*4, stream);
  hipMemsetAsync(x2raw, 0, (size_t)BB*D_F*4, stream);
  count_deg_k<<<EB, 256, 0, stream>>>(ei, deg, EDG);
  scan_block_k<<<NB, 256, 0, stream>>>(deg, incl, bsum, NNODES);
  scan_tot_k<<<1, 512, 0, stream>>>(bsum, boff, NB);
  csr_fin_k<<<NB, 256, 0, stream>>>(incl, deg, boff, rowptr, cursor, NNODES, 2*EDG);
  fill_k<<<EB, 256, 0, stream>>>(ei, erel, cursor, adj, arel, EDG);

  // ---- GCN layer 1 ----
  {
    dim3 grid((GC1_F+63)/64, (NNODES+63)/64, 1);
    gemm64<0,0,false><<<grid, 256, 0, stream>>>(emb_e, INIT_F, gc1_W, GC1_F, S1, GC1_F,
                                                nullptr, NNODES, GC1_F, INIT_F, INIT_F);
  }
  gcn_gather_k<<<NNODES, 192, 0, stream>>>(S1, rowptr, adj, arel, alpha1,
                                           gc1_b, bn3_g, bn3_b, H1, GC1_F);

  // ---- GCN layer 2 ----
  {
    dim3 grid((D_F+63)/64, (NNODES+63)/64, 1);
    gemm64<0,0,false><<<grid, 256, 0, stream>>>(H1, GC1_F, gc2_W, D_F, S2, D_F,
                                                nullptr, NNODES, D_F, GC1_F, GC1_F);
  }
  gcn_gather_k<<<NNODES, 256, 0, stream>>>(S2, rowptr, adj, arel, alpha2,
                                           gc2_b, bn4_g, bn4_b, AE, D_F);

  // ---- conv head ----
  build_s_k<<<BB, 256, 0, stream>>>(e1, rel, AE, embrel, bn0_g, bn0_b, sbuf);
  {
    dim3 grid(CCH/8, BB);
    conv_bn_relu_k<<<grid, 256, 0, stream>>>(sbuf, conv_w, conv_b, bn1_g, bn1_b, convout);
  }
  // fc: 128 x 40000 @ 40000 x 200 (fc_w^T), split-K=32 with atomic accumulate
  {
    dim3 grid((D_F+63)/64, (BB+63)/64, 32);
    int klen = (40000 + 31)/32;   // 1250
    gemm64<0,3,true><<<grid, 256, 0, stream>>>(convout, CCH*D_F, fc_w, CCH*D_F, x2raw, D_F,
                                               nullptr, BB, D_F, CCH*D_F, klen);
  }
  fc_fin_k<<<(BB*D_F+255)/256, 256, 0, stream>>>(x2raw, fc_b, bn2_g, bn2_b, x2);

  // ---- NFM branch ----
  feats_k<<<BB, 256, 0, stream>>>(attr, AE, ssum, deep);
  {
    dim3 grid((D_F+63)/64, (BB+63)/64, 1);
    // nfm = lrelu(deep @ bi_w^T + bi_b)
    gemm64<1,0,true><<<grid, 256, 0, stream>>>(deep, D_F, bi_w, D_F, nfm, D_F,
                                               bi_b, BB, D_F, D_F, D_F);
    // nfm += lrelu(ssum @ si_w^T + si_b)
    gemm64<1,1,true><<<grid, 256, 0, stream>>>(ssum, D_F, si_w, D_F, nfm, D_F,
                                               si_b, BB, D_F, D_F, D_F);
    // userb = nfm @ cs_w[:, :200]^T        (raw)
    gemm64<0,0,true><<<grid, 256, 0, stream>>>(nfm, D_F, cs_w, 2*D_F, userb, D_F,
                                               nullptr, BB, D_F, D_F, D_F);
    // userb = lrelu(userb + x2 @ cs_w[:, 200:]^T + cs_b)
    gemm64<1,2,true><<<grid, 256, 0, stream>>>(x2, D_F, cs_w + D_F, 2*D_F, userb, D_F,
                                               cs_b, BB, D_F, D_F, D_F);
  }

  // ---- outputs ----
  {
    // pred = sigmoid(userb @ all_emb^T) : M=128, N=100000, K=200
    dim3 grid((NNODES+63)/64, (BB+63)/64, 1);
    gemm64<2,0,true><<<grid, 256, 0, stream>>>(userb, D_F, AE, D_F, pred_out, NNODES,
                                               nullptr, BB, NNODES, D_F, D_F);
  }
  {
    // clusters = sigmoid(userb @ fc2_w^T + fc2_b) : M=128, N=16, K=200
    dim3 grid(1, (BB+63)/64, 1);
    gemm64<2,0,true><<<grid, 256, 0, stream>>>(userb, D_F, fc2_w, D_F, clus_out, NCL,
                                               fc2_b, BB, NCL, D_F, D_F);
  }
}

// Round 2
// 1376.727 us; speedup vs baseline: 1.1743x; 1.1743x over previous
//
#include <hip/hip_runtime.h>
#include <hip/hip_bf16.h>
#include <math.h>

// Problem constants (from reference setup_inputs)
#define NNODES 100000
#define INIT_F 100
#define GC1_F  150
#define D_F    200
#define CCH    200
#define BB     128
#define NA_    8
#define EDG    500000
#define NCL    16

// padded pitches (in float4 units) for GCN feature rows
#define P1_4   38   // 152 floats >= 150
#define P2_4   50   // 200 floats == 200

// ---------------- CSR build ----------------

__global__ void count_deg_k(const int* __restrict__ ei, int* __restrict__ deg, int E){
  int e = blockIdx.x*256 + threadIdx.x;
  if (e >= E) return;
  atomicAdd(&deg[ei[e]], 1);
  atomicAdd(&deg[ei[E+e]], 1);
}

__global__ void scan_block_k(const int* __restrict__ deg, int* __restrict__ incl,
                             int* __restrict__ bsum, int n){
  __shared__ int s[256];
  int t = threadIdx.x;
  int i = blockIdx.x*256 + t;
  int v = (i < n) ? deg[i] : 0;
  s[t] = v; __syncthreads();
  for (int off = 1; off < 256; off <<= 1){
    int x = (t >= off) ? s[t-off] : 0;
    __syncthreads();
    s[t] += x; __syncthreads();
  }
  if (i < n) incl[i] = s[t];
  if (t == 255) bsum[blockIdx.x] = s[255];
}

__global__ void scan_tot_k(const int* __restrict__ bsum, int* __restrict__ boff, int nb){
  __shared__ int s[512];
  int t = threadIdx.x;
  s[t] = (t < nb) ? bsum[t] : 0; __syncthreads();
  for (int off = 1; off < 512; off <<= 1){
    int x = (t >= off) ? s[t-off] : 0;
    __syncthreads();
    s[t] += x; __syncthreads();
  }
  if (t < nb) boff[t] = s[t] - bsum[t];   // exclusive block offset
}

__global__ void csr_fin_k(const int* __restrict__ incl, const int* __restrict__ deg,
                          const int* __restrict__ boff, int* __restrict__ rowptr,
                          int* __restrict__ cursor, int n, int total){
  int i = blockIdx.x*256 + threadIdx.x;
  if (i < n){
    int ex = incl[i] - deg[i] + boff[i >> 8];
    rowptr[i] = ex; cursor[i] = ex;
  }
  if (i == 0) rowptr[n] = total;
}

__global__ void fill_k(const int* __restrict__ ei, const int* __restrict__ erel,
                       int* __restrict__ cursor, int* __restrict__ adj,
                       int* __restrict__ arel, int E){
  int e = blockIdx.x*256 + threadIdx.x;
  if (e >= E) return;
  int r = ei[e], c = ei[E+e], rl = erel[e];
  int p = atomicAdd(&cursor[r], 1); adj[p] = c; arel[p] = rl;
  int q = atomicAdd(&cursor[c], 1); adj[q] = r; arel[q] = rl;
}

// ---------------- GCN gather, float4 + 4-neighbor unroll ----------------
// One wave per node; lane < F4 holds one float4 chunk of the feature row.
// 4 independent 16B loads in flight per lane -> latency-hiding via MLP.
// out[v][f] = tanh( (sum_j alpha[rel_j]*sup[u_j][f] + gb[f]) * (bng[f]*inv) + bnb[f] )

__global__ __launch_bounds__(256) void gcn_gather_v4(
    const float4* __restrict__ sup, const int* __restrict__ rowptr,
    const int* __restrict__ adj, const int* __restrict__ arel,
    const float* __restrict__ alpha, const float* __restrict__ gb,
    const float* __restrict__ bng, const float* __restrict__ bnb,
    float4* __restrict__ out, int F4, int F)
{
  int wave = threadIdx.x >> 6;
  int lane = threadIdx.x & 63;
  int v = blockIdx.x*4 + wave;
  if (v >= NNODES) return;
  int s = rowptr[v], e = rowptr[v+1];
  bool act = lane < F4;
  float4 acc = make_float4(0.f,0.f,0.f,0.f);
  int j = s;
  for (; j + 4 <= e; j += 4){
    int u0 = adj[j], u1 = adj[j+1], u2 = adj[j+2], u3 = adj[j+3];
    float w0 = alpha[arel[j]],   w1 = alpha[arel[j+1]];
    float w2 = alpha[arel[j+2]], w3 = alpha[arel[j+3]];
    if (act){
      float4 a = sup[(long)u0*F4 + lane];
      float4 b = sup[(long)u1*F4 + lane];
      float4 c = sup[(long)u2*F4 + lane];
      float4 d = sup[(long)u3*F4 + lane];
      acc.x += w0*a.x + w1*b.x + w2*c.x + w3*d.x;
      acc.y += w0*a.y + w1*b.y + w2*c.y + w3*d.y;
      acc.z += w0*a.z + w1*b.z + w2*c.z + w3*d.z;
      acc.w += w0*a.w + w1*b.w + w2*c.w + w3*d.w;
    }
  }
  for (; j < e; j++){
    int u = adj[j];
    float w = alpha[arel[j]];
    if (act){
      float4 a = sup[(long)u*F4 + lane];
      acc.x += w*a.x; acc.y += w*a.y; acc.z += w*a.z; acc.w += w*a.w;
    }
  }
  if (act){
    const float inv = rsqrtf(1.0f + 1e-5f);
    float r[4] = {acc.x, acc.y, acc.z, acc.w};
    float o[4];
    int f0 = lane*4;
    #pragma unroll
    for (int c = 0; c < 4; c++){
      int f = f0 + c;
      if (f < F){
        float x = r[c] + gb[f];
        x = x * (bng[f]*inv) + bnb[f];
        o[c] = tanhf(x);
      } else o[c] = 0.f;
    }
    out[(long)v*F4 + lane] = make_float4(o[0], o[1], o[2], o[3]);
  }
}

// ---------------- generic 64x64 tiled fp32 GEMM ----------------
// C[M x N] = A[M x K] * B  ; BT: B stored as [N][K] (row stride ldb), else [K][N].
// ACT: 0 none, 1 leaky-relu, 2 sigmoid.
// MODE: 0 store act(dot+bias); 1 C += act(dot+bias); 2 C = act(C + dot + bias); 3 atomicAdd(C, dot)

template<int ACT, int MODE, bool BT>
__global__ __launch_bounds__(256) void gemm64(
    const float* __restrict__ A, int lda,
    const float* __restrict__ Bm, int ldb,
    float* __restrict__ Cm, int ldc,
    const float* __restrict__ bias,
    int M, int N, int K, int klen)
{
  __shared__ float As[16][68];
  __shared__ float Bs[16][68];
  int tid = threadIdx.x;
  int tm = tid >> 4, tn = tid & 15;
  int m0 = blockIdx.y*64, n0 = blockIdx.x*64;
  int k0 = blockIdx.z * klen;
  int kend = min(k0 + klen, K);
  float acc[4][4] = {};

  for (int ks = k0; ks < kend; ks += 16){
    #pragma unroll
    for (int i = 0; i < 4; i++){
      int idx = tid + 256*i;
      int m = idx & 63, k = idx >> 6;
      int gm = m0 + m, gk = ks + k;
      As[k][m] = (gm < M && gk < kend) ? A[(long)gm*lda + gk] : 0.f;
    }
    #pragma unroll
    for (int i = 0; i < 4; i++){
      int idx = tid + 256*i;
      int n = idx & 63, k = idx >> 6;
      int gn = n0 + n, gk = ks + k;
      float v = 0.f;
      if (gn < N && gk < kend)
        v = BT ? Bm[(long)gn*ldb + gk] : Bm[(long)gk*ldb + gn];
      Bs[k][n] = v;
    }
    __syncthreads();
    #pragma unroll
    for (int kk = 0; kk < 16; kk++){
      float a[4], b[4];
      #pragma unroll
      for (int i = 0; i < 4; i++) a[i] = As[kk][tm*4+i];
      #pragma unroll
      for (int i = 0; i < 4; i++) b[i] = Bs[kk][tn*4+i];
      #pragma unroll
      for (int i = 0; i < 4; i++)
        #pragma unroll
        for (int j = 0; j < 4; j++)
          acc[i][j] += a[i]*b[j];
    }
    __syncthreads();
  }

  #pragma unroll
  for (int i = 0; i < 4; i++){
    int gm = m0 + tm*4 + i; if (gm >= M) continue;
    #pragma unroll
    for (int j = 0; j < 4; j++){
      int gn = n0 + tn*4 + j; if (gn >= N) continue;
      long co = (long)gm*ldc + gn;
      float x = acc[i][j];
      if (MODE == 3){ atomicAdd(&Cm[co], x); continue; }
      if (MODE == 2) x += Cm[co];
      if (bias) x += bias[gn];
      if (ACT == 1) x = (x >= 0.f) ? x : 0.01f*x;
      else if (ACT == 2) x = 1.f/(1.f + __expf(-x));
      float r = x;
      if (MODE == 1) r = Cm[co] + x;
      Cm[co] = r;
    }
  }
}

// ---------------- small fused kernels ----------------

// s[b][0][:] = bn0(all_emb[e1[b]]), s[b][1][:] = bn0(emb_rel[rel[b]])
__global__ void build_s_k(const int* __restrict__ e1, const int* __restrict__ rel,
                          const float* __restrict__ AE, const float* __restrict__ embrel,
                          const float* __restrict__ g0, const float* __restrict__ b0,
                          float* __restrict__ s){
  int b = blockIdx.x, t = threadIdx.x;
  if (t >= D_F) return;
  const float inv = rsqrtf(1.0f + 1e-5f);
  s[(b*2+0)*D_F + t] = AE[(long)e1[b]*D_F + t] * (g0[0]*inv) + b0[0];
  s[(b*2+1)*D_F + t] = embrel[(long)rel[b]*D_F + t] * (g0[1]*inv) + b0[1];
}

// conv1d(K=5, pad=2, 2 in-ch) + bias + bn1 + relu
__global__ void conv_bn_relu_k(const float* __restrict__ s, const float* __restrict__ cw,
                               const float* __restrict__ cb, const float* __restrict__ g1,
                               const float* __restrict__ b1, float* __restrict__ out){
  __shared__ float sh[2][D_F];
  int b = blockIdx.y, c0 = blockIdx.x*8, t = threadIdx.x;
  if (t < D_F){
    sh[0][t] = s[(b*2+0)*D_F + t];
    sh[1][t] = s[(b*2+1)*D_F + t];
  }
  __syncthreads();
  if (t >= D_F) return;
  const float inv = rsqrtf(1.0f + 1e-5f);
  for (int cc = 0; cc < 8; cc++){
    int c = c0 + cc;
    float sum = cb[c];
    #pragma unroll
    for (int i = 0; i < 2; i++){
      #pragma unroll
      for (int k = 0; k < 5; k++){
        int h = t + k - 2;
        float sv = (h >= 0 && h < D_F) ? sh[i][h] : 0.f;
        sum += sv * cw[(c*2+i)*5 + k];
      }
    }
    float x = sum * (g1[c]*inv) + b1[c];
    out[((long)b*CCH + c)*D_F + t] = fmaxf(x, 0.f);
  }
}

// x2 = relu( (fcraw + fc_b) * bn2_g*inv + bn2_b )
__global__ void fc_fin_k(const float* __restrict__ raw, const float* __restrict__ fb,
                         const float* __restrict__ g, const float* __restrict__ bb,
                         float* __restrict__ x2){
  int i = blockIdx.x*256 + threadIdx.x;
  if (i >= BB*D_F) return;
  int j = i % D_F;
  const float inv = rsqrtf(1.0f + 1e-5f);
  float x = (raw[i] + fb[j]) * (g[j]*inv) + bb[j];
  x2[i] = fmaxf(x, 0.f);
}

// ssum / deep from attr gather
__global__ void feats_k(const int* __restrict__ attr, const float* __restrict__ AE,
                        float* __restrict__ ssum, float* __restrict__ deep){
  int b = blockIdx.x, t = threadIdx.x;
  if (t >= D_F) return;
  float s = 0.f, sq = 0.f;
  #pragma unroll
  for (int a = 0; a < NA_; a++){
    int id = attr[b*NA_ + a];
    float v = AE[(long)id*D_F + t];
    s += v; sq += v*v;
  }
  ssum[b*D_F + t] = s;
  deep[b*D_F + t] = 0.5f*(s*s - sq);
}

// ---------------- launch ----------------

extern "C" void kernel_launch(void* const* d_in, const int* in_sizes, int n_in,
                              void* d_out, int out_size, void* d_ws, size_t ws_size,
                              hipStream_t stream) {
  const int* e1       = (const int*)d_in[0];
  const int* rel      = (const int*)d_in[1];
  const int* attr     = (const int*)d_in[2];
  // d_in[3] = X (arange, identity gather) — unused
  const int* ei       = (const int*)d_in[4];
  const int* erel     = (const int*)d_in[5];
  const float* emb_e  = (const float*)d_in[6];
  const float* embrel = (const float*)d_in[7];
  const float* alpha1 = (const float*)d_in[8];
  const float* alpha2 = (const float*)d_in[9];
  const float* gc1_W  = (const float*)d_in[10];
  const float* gc1_b  = (const float*)d_in[11];
  const float* gc2_W  = (const float*)d_in[12];
  const float* gc2_b  = (const float*)d_in[13];
  const float* bn3_g  = (const float*)d_in[14];
  const float* bn3_b  = (const float*)d_in[15];
  const float* bn4_g  = (const float*)d_in[16];
  const float* bn4_b  = (const float*)d_in[17];
  const float* bn0_g  = (const float*)d_in[18];
  const float* bn0_b  = (const float*)d_in[19];
  const float* conv_w = (const float*)d_in[20];
  const float* conv_b = (const float*)d_in[21];
  const float* bn1_g  = (const float*)d_in[22];
  const float* bn1_b  = (const float*)d_in[23];
  const float* fc_w   = (const float*)d_in[24];
  const float* fc_b   = (const float*)d_in[25];
  const float* bn2_g  = (const float*)d_in[26];
  const float* bn2_b  = (const float*)d_in[27];
  const float* bi_w   = (const float*)d_in[28];
  const float* bi_b   = (const float*)d_in[29];
  const float* si_w   = (const float*)d_in[30];
  const float* si_b   = (const float*)d_in[31];
  const float* cs_w   = (const float*)d_in[32];
  const float* cs_b   = (const float*)d_in[33];
  const float* fc2_w  = (const float*)d_in[34];
  const float* fc2_b  = (const float*)d_in[35];

  float* pred_out = (float*)d_out;                       // 128 x 100000
  float* clus_out = (float*)d_out + (long)BB*NNODES;     // 128 x 16

  // workspace layout
  char* w = (char*)d_ws;
  size_t off = 0;
  auto alloc = [&](size_t bytes) -> void* {
    off = (off + 255) & ~(size_t)255;
    void* p = w + off;
    off += bytes;
    return p;
  };
  float* regionA = (float*)alloc((size_t)NNODES*D_F*4);  // S1(pitch152), S2(200), convout
  float* regionB = (float*)alloc((size_t)NNODES*D_F*4);  // H1(pitch152), all_emb(200)
  int* deg    = (int*)alloc((size_t)NNODES*4);
  int* incl   = (int*)alloc((size_t)NNODES*4);
  int* bsum   = (int*)alloc(512*4);
  int* boff   = (int*)alloc(512*4);
  int* rowptr = (int*)alloc((size_t)(NNODES+1)*4);
  int* cursor = (int*)alloc((size_t)NNODES*4);
  int* adj    = (int*)alloc((size_t)2*EDG*4);
  int* arel   = (int*)alloc((size_t)2*EDG*4);
  float* sbuf   = (float*)alloc((size_t)BB*2*D_F*4);
  float* x2raw  = (float*)alloc((size_t)BB*D_F*4);
  float* x2     = (float*)alloc((size_t)BB*D_F*4);
  float* ssum   = (float*)alloc((size_t)BB*D_F*4);
  float* deep   = (float*)alloc((size_t)BB*D_F*4);
  float* nfm    = (float*)alloc((size_t)BB*D_F*4);
  float* userb  = (float*)alloc((size_t)BB*D_F*4);

  float* S1 = regionA;           // N x 152 (padded pitch)
  float* S2 = regionA;           // N x 200 (S1 dead by then)
  float* convout = regionA;      // 128 x 200 x 200 (S2 dead by then)
  float* H1 = regionB;           // N x 152 (padded pitch)
  float* AE = regionB;           // N x 200 (H1 dead by then)

  const int EB = (EDG + 255)/256;           // 1954
  const int NB = (NNODES + 255)/256;        // 391
  const int GGB = (NNODES + 3)/4;           // 4 nodes (waves) per block

  // ---- CSR build ----
  hipMemsetAsync(deg, 0, (size_t)NNODES*4, stream);
  hipMemsetAsync(x2raw, 0, (size_t)BB*D_F*4, stream);
  count_deg_k<<<EB, 256, 0, stream>>>(ei, deg, EDG);
  scan_block_k<<<NB, 256, 0, stream>>>(deg, incl, bsum, NNODES);
  scan_tot_k<<<1, 512, 0, stream>>>(bsum, boff, NB);
  csr_fin_k<<<NB, 256, 0, stream>>>(incl, deg, boff, rowptr, cursor, NNODES, 2*EDG);
  fill_k<<<EB, 256, 0, stream>>>(ei, erel, cursor, adj, arel, EDG);

  // ---- GCN layer 1 ----
  {
    dim3 grid((GC1_F+63)/64, (NNODES+63)/64, 1);
    gemm64<0,0,false><<<grid, 256, 0, stream>>>(emb_e, INIT_F, gc1_W, GC1_F, S1, P1_4*4,
                                                nullptr, NNODES, GC1_F, INIT_F, INIT_F);
  }
  gcn_gather_v4<<<GGB, 256, 0, stream>>>((const float4*)S1, rowptr, adj, arel, alpha1,
                                         gc1_b, bn3_g, bn3_b, (float4*)H1, P1_4, GC1_F);

  // ---- GCN layer 2 ----
  {
    dim3 grid((D_F+63)/64, (NNODES+63)/64, 1);
    gemm64<0,0,false><<<grid, 256, 0, stream>>>(H1, P1_4*4, gc2_W, D_F, S2, D_F,
                                                nullptr, NNODES, D_F, GC1_F, GC1_F);
  }
  gcn_gather_v4<<<GGB, 256, 0, stream>>>((const float4*)S2, rowptr, adj, arel, alpha2,
                                         gc2_b, bn4_g, bn4_b, (float4*)AE, P2_4, D_F);

  // ---- conv head ----
  build_s_k<<<BB, 256, 0, stream>>>(e1, rel, AE, embrel, bn0_g, bn0_b, sbuf);
  {
    dim3 grid(CCH/8, BB);
    conv_bn_relu_k<<<grid, 256, 0, stream>>>(sbuf, conv_w, conv_b, bn1_g, bn1_b, convout);
  }
  // fc: 128 x 40000 @ 40000 x 200 (fc_w^T), split-K=32 with atomic accumulate
  {
    dim3 grid((D_F+63)/64, (BB+63)/64, 32);
    int klen = (40000 + 31)/32;   // 1250
    gemm64<0,3,true><<<grid, 256, 0, stream>>>(convout, CCH*D_F, fc_w, CCH*D_F, x2raw, D_F,
                                               nullptr, BB, D_F, CCH*D_F, klen);
  }
  fc_fin_k<<<(BB*D_F+255)/256, 256, 0, stream>>>(x2raw, fc_b, bn2_g, bn2_b, x2);

  // ---- NFM branch ----
  feats_k<<<BB, 256, 0, stream>>>(attr, AE, ssum, deep);
  {
    dim3 grid((D_F+63)/64, (BB+63)/64, 1);
    // nfm = lrelu(deep @ bi_w^T + bi_b)
    gemm64<1,0,true><<<grid, 256, 0, stream>>>(deep, D_F, bi_w, D_F, nfm, D_F,
                                               bi_b, BB, D_F, D_F, D_F);
    // nfm += lrelu(ssum @ si_w^T + si_b)
    gemm64<1,1,true><<<grid, 256, 0, stream>>>(ssum, D_F, si_w, D_F, nfm, D_F,
                                               si_b, BB, D_F, D_F, D_F);
    // userb = nfm @ cs_w[:, :200]^T        (raw)
    gemm64<0,0,true><<<grid, 256, 0, stream>>>(nfm, D_F, cs_w, 2*D_F, userb, D_F,
                                               nullptr, BB, D_F, D_F, D_F);
    // userb = lrelu(userb + x2 @ cs_w[:, 200:]^T + cs_b)
    gemm64<1,2,true><<<grid, 256, 0, stream>>>(x2, D_F, cs_w + D_F, 2*D_F, userb, D_F,
                                               cs_b, BB, D_F, D_F, D_F);
  }

  // ---- outputs ----
  {
    // pred = sigmoid(userb @ all_emb^T) : M=128, N=100000, K=200
    dim3 grid((NNODES+63)/64, (BB+63)/64, 1);
    gemm64<2,0,true><<<grid, 256, 0, stream>>>(userb, D_F, AE, D_F, pred_out, NNODES,
                                               nullptr, BB, NNODES, D_F, D_F);
  }
  {
    // clusters = sigmoid(userb @ fc2_w^T + fc2_b) : M=128, N=16, K=200
    dim3 grid(1, (BB+63)/64, 1);
    gemm64<2,0,true><<<grid, 256, 0, stream>>>(userb, D_F, fc2_w, D_F, clus_out, NCL,
                                               fc2_b, BB, NCL, D_F, D_F);
  }
}

// Round 3
// 1044.396 us; speedup vs baseline: 1.5480x; 1.3182x over previous
//
#include <hip/hip_runtime.h>
#include <hip/hip_bf16.h>
#include <math.h>

// Problem constants (from reference setup_inputs)
#define NNODES 100000
#define INIT_F 100
#define GC1_F  150
#define D_F    200
#define CCH    200
#define BB     128
#define NA_    8
#define EDG    500000
#define NCL    16

#define MROWS  100032   // 1563 * 64, padded row count for MFMA A/B operands

// bf16 K-padded pitches (elements)
#define KP1    128      // gcn1: K=100 -> 128
#define KP2    160      // gcn2: K=150 -> 160
#define KPP    224      // pred: K=200 -> 224

typedef __attribute__((ext_vector_type(8))) __bf16 bf16x8;
typedef __attribute__((ext_vector_type(4))) float  f32x4;

// ---------------- CSR build ----------------

__global__ void count_deg_k(const int* __restrict__ ei, int* __restrict__ deg, int E){
  int e = blockIdx.x*256 + threadIdx.x;
  if (e >= E) return;
  atomicAdd(&deg[ei[e]], 1);
  atomicAdd(&deg[ei[E+e]], 1);
}

__global__ void scan_block_k(const int* __restrict__ deg, int* __restrict__ incl,
                             int* __restrict__ bsum, int n){
  __shared__ int s[256];
  int t = threadIdx.x;
  int i = blockIdx.x*256 + t;
  int v = (i < n) ? deg[i] : 0;
  s[t] = v; __syncthreads();
  for (int off = 1; off < 256; off <<= 1){
    int x = (t >= off) ? s[t-off] : 0;
    __syncthreads();
    s[t] += x; __syncthreads();
  }
  if (i < n) incl[i] = s[t];
  if (t == 255) bsum[blockIdx.x] = s[255];
}

__global__ void scan_tot_k(const int* __restrict__ bsum, int* __restrict__ boff, int nb){
  __shared__ int s[512];
  int t = threadIdx.x;
  s[t] = (t < nb) ? bsum[t] : 0; __syncthreads();
  for (int off = 1; off < 512; off <<= 1){
    int x = (t >= off) ? s[t-off] : 0;
    __syncthreads();
    s[t] += x; __syncthreads();
  }
  if (t < nb) boff[t] = s[t] - bsum[t];   // exclusive block offset
}

__global__ void csr_fin_k(const int* __restrict__ incl, const int* __restrict__ deg,
                          const int* __restrict__ boff, int* __restrict__ rowptr,
                          int* __restrict__ cursor, int n, int total){
  int i = blockIdx.x*256 + threadIdx.x;
  if (i < n){
    int ex = incl[i] - deg[i] + boff[i >> 8];
    rowptr[i] = ex; cursor[i] = ex;
  }
  if (i == 0) rowptr[n] = total;
}

__global__ void fill_k(const int* __restrict__ ei, const int* __restrict__ erel,
                       int* __restrict__ cursor, int* __restrict__ adj,
                       int* __restrict__ arel, int E){
  int e = blockIdx.x*256 + threadIdx.x;
  if (e >= E) return;
  int r = ei[e], c = ei[E+e], rl = erel[e];
  int p = atomicAdd(&cursor[r], 1); adj[p] = c; arel[p] = rl;
  int q = atomicAdd(&cursor[c], 1); adj[q] = r; arel[q] = rl;
}

// ---------------- GCN gather: fp32 float4 in, bf16 out ----------------
// PIN4: input pitch in float4; NRD: read lanes; WL: bf16-write lanes (4 elems each);
// PHO: bf16 out pitch (elems); F: true feature count.
// out[v][f] = tanh( (sum_j alpha[rel_j]*sup[u_j][f] + gb[f]) * (bng[f]*inv) + bnb[f] )

template<int PIN4, int NRD, int WL, int PHO, int F>
__global__ __launch_bounds__(256) void gcn_gather_b(
    const float4* __restrict__ sup, const int* __restrict__ rowptr,
    const int* __restrict__ adj, const int* __restrict__ arel,
    const float* __restrict__ alpha, const float* __restrict__ gb,
    const float* __restrict__ bng, const float* __restrict__ bnb,
    __bf16* __restrict__ outH)
{
  int wave = threadIdx.x >> 6;
  int lane = threadIdx.x & 63;
  int v = blockIdx.x*4 + wave;
  if (v >= NNODES) return;
  int s = rowptr[v], e = rowptr[v+1];
  bool act = lane < NRD;
  float4 acc = make_float4(0.f,0.f,0.f,0.f);
  int j = s;
  for (; j + 4 <= e; j += 4){
    int u0 = adj[j], u1 = adj[j+1], u2 = adj[j+2], u3 = adj[j+3];
    float w0 = alpha[arel[j]],   w1 = alpha[arel[j+1]];
    float w2 = alpha[arel[j+2]], w3 = alpha[arel[j+3]];
    if (act){
      float4 a = sup[(long)u0*PIN4 + lane];
      float4 b = sup[(long)u1*PIN4 + lane];
      float4 c = sup[(long)u2*PIN4 + lane];
      float4 d = sup[(long)u3*PIN4 + lane];
      acc.x += w0*a.x + w1*b.x + w2*c.x + w3*d.x;
      acc.y += w0*a.y + w1*b.y + w2*c.y + w3*d.y;
      acc.z += w0*a.z + w1*b.z + w2*c.z + w3*d.z;
      acc.w += w0*a.w + w1*b.w + w2*c.w + w3*d.w;
    }
  }
  for (; j < e; j++){
    int u = adj[j];
    float w = alpha[arel[j]];
    if (act){
      float4 a = sup[(long)u*PIN4 + lane];
      acc.x += w*a.x; acc.y += w*a.y; acc.z += w*a.z; acc.w += w*a.w;
    }
  }
  if (lane < WL){
    const float inv = rsqrtf(1.0f + 1e-5f);
    float r[4] = {acc.x, acc.y, acc.z, acc.w};
    __bf16 ob[4] __attribute__((aligned(8)));
    int f0 = lane*4;
    #pragma unroll
    for (int c = 0; c < 4; c++){
      int f = f0 + c;
      if (f < F){
        float x = r[c] + gb[f];
        x = x * (bng[f]*inv) + bnb[f];
        ob[c] = (__bf16)tanhf(x);
      } else ob[c] = (__bf16)0.f;
    }
    *reinterpret_cast<uint2*>(outH + (long)v*PHO + lane*4) =
        *reinterpret_cast<const uint2*>(ob);
  }
}

// ---------------- bf16 MFMA GEMM ----------------
// C[M x N](fp32) = A[M x KP](bf16 row-major) * Bt[N x KP](bf16 row-major, B^T)
// Block: 4 waves; wave w owns rows [m0+w*16, +16) x cols [n0, n0+64).
// Fragment layouts (guide §3, m89/m91-verified):
//   A/B operand: lane l -> free idx (m or n) = l&15, k = (l>>4)*8 + j, j=0..7
//   C/D: col = l&15, row = (l>>4)*4 + reg
// ACT: 0 none, 2 sigmoid. Pad rows of A/Bt may hold garbage; epilogue guards
// gm<M / gn<N (MFMA outputs are per-row/col independent, garbage can't leak).

template<int KP, int ACT>
__global__ __launch_bounds__(256) void mfma_gemm(
    const __bf16* __restrict__ A, const __bf16* __restrict__ Bt,
    float* __restrict__ C, long ldc, int M, int N)
{
  int w = threadIdx.x >> 6, l = threadIdx.x & 63;
  int m0 = blockIdx.y*64 + w*16;
  int n0 = blockIdx.x*64;
  int ml = l & 15, kq = l >> 4;
  const __bf16* Ap = A  + (long)(m0 + ml)*KP + kq*8;
  const __bf16* Bp = Bt + (long)(n0 + ml)*KP + kq*8;
  f32x4 acc[4] = {};
  #pragma unroll
  for (int k0 = 0; k0 < KP; k0 += 32){
    bf16x8 a = *(const bf16x8*)(Ap + k0);
    #pragma unroll
    for (int t = 0; t < 4; t++){
      bf16x8 b = *(const bf16x8*)(Bp + (long)t*16*KP + k0);
      acc[t] = __builtin_amdgcn_mfma_f32_16x16x32_bf16(a, b, acc[t], 0, 0, 0);
    }
  }
  int mr = m0 + kq*4;
  #pragma unroll
  for (int t = 0; t < 4; t++){
    int gn = n0 + t*16 + ml;
    if (gn >= N) continue;
    #pragma unroll
    for (int r = 0; r < 4; r++){
      int gm = mr + r;
      if (gm < M){
        float x = acc[t][r];
        if (ACT == 2) x = 1.f/(1.f + __expf(-x));
        C[(long)gm*ldc + gn] = x;
      }
    }
  }
}

// ---------------- conversion helpers ----------------

// rows x cols fp32 -> rows x colsP bf16 (zero pad cols)
__global__ void conv_a_bf16_k(const float* __restrict__ src, __bf16* __restrict__ dst,
                              int cols, int colsP){
  long r = blockIdx.x;
  for (int j = threadIdx.x; j < colsP; j += blockDim.x)
    dst[r*colsP + j] = (j < cols) ? (__bf16)src[r*cols + j] : (__bf16)0.f;
}

// W[K x N] fp32 -> Bt[Np x Kp] bf16 (transpose + zero pad)
__global__ void transpose_w_k(const float* __restrict__ W, __bf16* __restrict__ Bt,
                              int K, int N, int Kp){
  int n = blockIdx.x;
  for (int k = threadIdx.x; k < Kp; k += blockDim.x){
    float v = (k < K && n < N) ? W[(long)k*N + n] : 0.f;
    Bt[(long)n*Kp + k] = (__bf16)v;
  }
}

// ---------------- small fused kernels ----------------

// s[b][0][:] = bn0(AEh[e1[b]]), s[b][1][:] = bn0(emb_rel[rel[b]])
__global__ void build_s_k(const int* __restrict__ e1, const int* __restrict__ rel,
                          const __bf16* __restrict__ AEh, const float* __restrict__ embrel,
                          const float* __restrict__ g0, const float* __restrict__ b0,
                          float* __restrict__ s){
  int b = blockIdx.x, t = threadIdx.x;
  if (t >= D_F) return;
  const float inv = rsqrtf(1.0f + 1e-5f);
  float ev = (float)AEh[(long)e1[b]*KPP + t];
  s[(b*2+0)*D_F + t] = ev * (g0[0]*inv) + b0[0];
  s[(b*2+1)*D_F + t] = embrel[(long)rel[b]*D_F + t] * (g0[1]*inv) + b0[1];
}

// conv1d(K=5, pad=2, 2 in-ch) + bias + bn1 + relu
__global__ void conv_bn_relu_k(const float* __restrict__ s, const float* __restrict__ cw,
                               const float* __restrict__ cb, const float* __restrict__ g1,
                               const float* __restrict__ b1, float* __restrict__ out){
  __shared__ float sh[2][D_F];
  int b = blockIdx.y, c0 = blockIdx.x*8, t = threadIdx.x;
  if (t < D_F){
    sh[0][t] = s[(b*2+0)*D_F + t];
    sh[1][t] = s[(b*2+1)*D_F + t];
  }
  __syncthreads();
  if (t >= D_F) return;
  const float inv = rsqrtf(1.0f + 1e-5f);
  for (int cc = 0; cc < 8; cc++){
    int c = c0 + cc;
    float sum = cb[c];
    #pragma unroll
    for (int i = 0; i < 2; i++){
      #pragma unroll
      for (int k = 0; k < 5; k++){
        int h = t + k - 2;
        float sv = (h >= 0 && h < D_F) ? sh[i][h] : 0.f;
        sum += sv * cw[(c*2+i)*5 + k];
      }
    }
    float x = sum * (g1[c]*inv) + b1[c];
    out[((long)b*CCH + c)*D_F + t] = fmaxf(x, 0.f);
  }
}

// x2 = relu( (fcraw + fc_b) * bn2_g*inv + bn2_b )
__global__ void fc_fin_k(const float* __restrict__ raw, const float* __restrict__ fb,
                         const float* __restrict__ g, const float* __restrict__ bb,
                         float* __restrict__ x2){
  int i = blockIdx.x*256 + threadIdx.x;
  if (i >= BB*D_F) return;
  int j = i % D_F;
  const float inv = rsqrtf(1.0f + 1e-5f);
  float x = (raw[i] + fb[j]) * (g[j]*inv) + bb[j];
  x2[i] = fmaxf(x, 0.f);
}

// ssum / deep from attr gather (reads bf16 AEh)
__global__ void feats_k(const int* __restrict__ attr, const __bf16* __restrict__ AEh,
                        float* __restrict__ ssum, float* __restrict__ deep){
  int b = blockIdx.x, t = threadIdx.x;
  if (t >= D_F) return;
  float s = 0.f, sq = 0.f;
  #pragma unroll
  for (int a = 0; a < NA_; a++){
    int id = attr[b*NA_ + a];
    float v = (float)AEh[(long)id*KPP + t];
    s += v; sq += v*v;
  }
  ssum[b*D_F + t] = s;
  deep[b*D_F + t] = 0.5f*(s*s - sq);
}

// ---------------- generic 64x64 tiled fp32 GEMM (small shapes only) ----------------

template<int ACT, int MODE, bool BT>
__global__ __launch_bounds__(256) void gemm64(
    const float* __restrict__ A, int lda,
    const float* __restrict__ Bm, int ldb,
    float* __restrict__ Cm, int ldc,
    const float* __restrict__ bias,
    int M, int N, int K, int klen)
{
  __shared__ float As[16][68];
  __shared__ float Bs[16][68];
  int tid = threadIdx.x;
  int tm = tid >> 4, tn = tid & 15;
  int m0 = blockIdx.y*64, n0 = blockIdx.x*64;
  int k0 = blockIdx.z * klen;
  int kend = min(k0 + klen, K);
  float acc[4][4] = {};

  for (int ks = k0; ks < kend; ks += 16){
    #pragma unroll
    for (int i = 0; i < 4; i++){
      int idx = tid + 256*i;
      int m = idx & 63, k = idx >> 6;
      int gm = m0 + m, gk = ks + k;
      As[k][m] = (gm < M && gk < kend) ? A[(long)gm*lda + gk] : 0.f;
    }
    #pragma unroll
    for (int i = 0; i < 4; i++){
      int idx = tid + 256*i;
      int n = idx & 63, k = idx >> 6;
      int gn = n0 + n, gk = ks + k;
      float v = 0.f;
      if (gn < N && gk < kend)
        v = BT ? Bm[(long)gn*ldb + gk] : Bm[(long)gk*ldb + gn];
      Bs[k][n] = v;
    }
    __syncthreads();
    #pragma unroll
    for (int kk = 0; kk < 16; kk++){
      float a[4], b[4];
      #pragma unroll
      for (int i = 0; i < 4; i++) a[i] = As[kk][tm*4+i];
      #pragma unroll
      for (int i = 0; i < 4; i++) b[i] = Bs[kk][tn*4+i];
      #pragma unroll
      for (int i = 0; i < 4; i++)
        #pragma unroll
        for (int j = 0; j < 4; j++)
          acc[i][j] += a[i]*b[j];
    }
    __syncthreads();
  }

  #pragma unroll
  for (int i = 0; i < 4; i++){
    int gm = m0 + tm*4 + i; if (gm >= M) continue;
    #pragma unroll
    for (int j = 0; j < 4; j++){
      int gn = n0 + tn*4 + j; if (gn >= N) continue;
      long co = (long)gm*ldc + gn;
      float x = acc[i][j];
      if (MODE == 3){ atomicAdd(&Cm[co], x); continue; }
      if (MODE == 2) x += Cm[co];
      if (bias) x += bias[gn];
      if (ACT == 1) x = (x >= 0.f) ? x : 0.01f*x;
      else if (ACT == 2) x = 1.f/(1.f + __expf(-x));
      float r = x;
      if (MODE == 1) r = Cm[co] + x;
      Cm[co] = r;
    }
  }
}

// ---------------- launch ----------------

extern "C" void kernel_launch(void* const* d_in, const int* in_sizes, int n_in,
                              void* d_out, int out_size, void* d_ws, size_t ws_size,
                              hipStream_t stream) {
  const int* e1       = (const int*)d_in[0];
  const int* rel      = (const int*)d_in[1];
  const int* attr     = (const int*)d_in[2];
  const int* ei       = (const int*)d_in[4];
  const int* erel     = (const int*)d_in[5];
  const float* emb_e  = (const float*)d_in[6];
  const float* embrel = (const float*)d_in[7];
  const float* alpha1 = (const float*)d_in[8];
  const float* alpha2 = (const float*)d_in[9];
  const float* gc1_W  = (const float*)d_in[10];
  const float* gc1_b  = (const float*)d_in[11];
  const float* gc2_W  = (const float*)d_in[12];
  const float* gc2_b  = (const float*)d_in[13];
  const float* bn3_g  = (const float*)d_in[14];
  const float* bn3_b  = (const float*)d_in[15];
  const float* bn4_g  = (const float*)d_in[16];
  const float* bn4_b  = (const float*)d_in[17];
  const float* bn0_g  = (const float*)d_in[18];
  const float* bn0_b  = (const float*)d_in[19];
  const float* conv_w = (const float*)d_in[20];
  const float* conv_b = (const float*)d_in[21];
  const float* bn1_g  = (const float*)d_in[22];
  const float* bn1_b  = (const float*)d_in[23];
  const float* fc_w   = (const float*)d_in[24];
  const float* fc_b   = (const float*)d_in[25];
  const float* bn2_g  = (const float*)d_in[26];
  const float* bn2_b  = (const float*)d_in[27];
  const float* bi_w   = (const float*)d_in[28];
  const float* bi_b   = (const float*)d_in[29];
  const float* si_w   = (const float*)d_in[30];
  const float* si_b   = (const float*)d_in[31];
  const float* cs_w   = (const float*)d_in[32];
  const float* cs_b   = (const float*)d_in[33];
  const float* fc2_w  = (const float*)d_in[34];
  const float* fc2_b  = (const float*)d_in[35];

  float* pred_out = (float*)d_out;                       // 128 x 100000
  float* clus_out = (float*)d_out + (long)BB*NNODES;     // 128 x 16

  char* w = (char*)d_ws;
  size_t off = 0;
  auto alloc = [&](size_t bytes) -> void* {
    off = (off + 255) & ~(size_t)255;
    void* p = w + off;
    off += bytes;
    return p;
  };
  // R1: S1 (100000 x 152 fp32 = 60.8MB), later AEh (MROWS x 224 bf16 = 44.8MB)
  void* R1 = alloc((size_t)NNODES*152*4);
  // R2: emb_h (MROWS x 128 bf16 = 25.6MB), later S2 (100000 x 200 fp32 = 80MB)
  void* R2 = alloc((size_t)NNODES*D_F*4);
  // R3: H1h (MROWS x 160 bf16 = 32MB), later convout (128x200x200 fp32 = 20.5MB)
  void* R3 = alloc((size_t)MROWS*KP2*2);

  int* deg    = (int*)alloc((size_t)NNODES*4);
  int* incl   = (int*)alloc((size_t)NNODES*4);
  int* bsum   = (int*)alloc(512*4);
  int* boff   = (int*)alloc(512*4);
  int* rowptr = (int*)alloc((size_t)(NNODES+1)*4);
  int* cursor = (int*)alloc((size_t)NNODES*4);
  int* adj    = (int*)alloc((size_t)2*EDG*4);
  int* arel   = (int*)alloc((size_t)2*EDG*4);
  __bf16* Bt1 = (__bf16*)alloc((size_t)192*KP1*2);
  __bf16* Bt2 = (__bf16*)alloc((size_t)256*KP2*2);
  __bf16* uh  = (__bf16*)alloc((size_t)BB*KPP*2);
  float* sbuf   = (float*)alloc((size_t)BB*2*D_F*4);
  float* x2raw  = (float*)alloc((size_t)BB*D_F*4);
  float* x2     = (float*)alloc((size_t)BB*D_F*4);
  float* ssum   = (float*)alloc((size_t)BB*D_F*4);
  float* deep   = (float*)alloc((size_t)BB*D_F*4);
  float* nfm    = (float*)alloc((size_t)BB*D_F*4);
  float* userb  = (float*)alloc((size_t)BB*D_F*4);

  float*  S1    = (float*)R1;     // pitch 152
  __bf16* AEh   = (__bf16*)R1;    // pitch 224
  __bf16* emb_h = (__bf16*)R2;    // pitch 128
  float*  S2    = (float*)R2;     // pitch 200
  __bf16* H1h   = (__bf16*)R3;    // pitch 160
  float*  convout = (float*)R3;   // 128 x 200 x 200

  const int EB = (EDG + 255)/256;
  const int NB = (NNODES + 255)/256;
  const int GGB = (NNODES + 3)/4;
  const int MT = MROWS/64;        // 1563

  // ---- CSR build ----
  hipMemsetAsync(deg, 0, (size_t)NNODES*4, stream);
  hipMemsetAsync(x2raw, 0, (size_t)BB*D_F*4, stream);
  count_deg_k<<<EB, 256, 0, stream>>>(ei, deg, EDG);
  scan_block_k<<<NB, 256, 0, stream>>>(deg, incl, bsum, NNODES);
  scan_tot_k<<<1, 512, 0, stream>>>(bsum, boff, NB);
  csr_fin_k<<<NB, 256, 0, stream>>>(incl, deg, boff, rowptr, cursor, NNODES, 2*EDG);
  fill_k<<<EB, 256, 0, stream>>>(ei, erel, cursor, adj, arel, EDG);

  // ---- operand prep ----
  conv_a_bf16_k<<<NNODES, 128, 0, stream>>>(emb_e, emb_h, INIT_F, KP1);
  transpose_w_k<<<192, 128, 0, stream>>>(gc1_W, Bt1, INIT_F, GC1_F, KP1);
  transpose_w_k<<<256, 128, 0, stream>>>(gc2_W, Bt2, GC1_F, D_F, KP2);

  // ---- GCN layer 1: S1 = emb_h @ gc1_W  (M=1e5, N=150, K=100) ----
  {
    dim3 grid(3, MT);
    mfma_gemm<KP1,0><<<grid, 256, 0, stream>>>(emb_h, Bt1, S1, 152, NNODES, GC1_F);
  }
  gcn_gather_b<38,38,40,KP2,GC1_F><<<GGB, 256, 0, stream>>>(
      (const float4*)S1, rowptr, adj, arel, alpha1, gc1_b, bn3_g, bn3_b, H1h);

  // ---- GCN layer 2: S2 = H1h @ gc2_W  (M=1e5, N=200, K=150) ----
  {
    dim3 grid(4, MT);
    mfma_gemm<KP2,0><<<grid, 256, 0, stream>>>(H1h, Bt2, S2, D_F, NNODES, D_F);
  }
  gcn_gather_b<50,50,56,KPP,D_F><<<GGB, 256, 0, stream>>>(
      (const float4*)S2, rowptr, adj, arel, alpha2, gc2_b, bn4_g, bn4_b, AEh);

  // ---- conv head ----
  build_s_k<<<BB, 256, 0, stream>>>(e1, rel, AEh, embrel, bn0_g, bn0_b, sbuf);
  {
    dim3 grid(CCH/8, BB);
    conv_bn_relu_k<<<grid, 256, 0, stream>>>(sbuf, conv_w, conv_b, bn1_g, bn1_b, convout);
  }
  // fc: 128 x 40000 @ fc_w^T, split-K=32 with atomic accumulate (fp32)
  {
    dim3 grid((D_F+63)/64, (BB+63)/64, 32);
    int klen = (40000 + 31)/32;
    gemm64<0,3,true><<<grid, 256, 0, stream>>>(convout, CCH*D_F, fc_w, CCH*D_F, x2raw, D_F,
                                               nullptr, BB, D_F, CCH*D_F, klen);
  }
  fc_fin_k<<<(BB*D_F+255)/256, 256, 0, stream>>>(x2raw, fc_b, bn2_g, bn2_b, x2);

  // ---- NFM branch ----
  feats_k<<<BB, 256, 0, stream>>>(attr, AEh, ssum, deep);
  {
    dim3 grid((D_F+63)/64, (BB+63)/64, 1);
    gemm64<1,0,true><<<grid, 256, 0, stream>>>(deep, D_F, bi_w, D_F, nfm, D_F,
                                               bi_b, BB, D_F, D_F, D_F);
    gemm64<1,1,true><<<grid, 256, 0, stream>>>(ssum, D_F, si_w, D_F, nfm, D_F,
                                               si_b, BB, D_F, D_F, D_F);
    gemm64<0,0,true><<<grid, 256, 0, stream>>>(nfm, D_F, cs_w, 2*D_F, userb, D_F,
                                               nullptr, BB, D_F, D_F, D_F);
    gemm64<1,2,true><<<grid, 256, 0, stream>>>(x2, D_F, cs_w + D_F, 2*D_F, userb, D_F,
                                               cs_b, BB, D_F, D_F, D_F);
  }

  // ---- outputs ----
  conv_a_bf16_k<<<BB, 256, 0, stream>>>(userb, uh, D_F, KPP);
  {
    // pred = sigmoid(uh @ AEh^T) : M=128, N=100000, K=200(->224)
    dim3 grid(MT, 2);
    mfma_gemm<KPP,2><<<grid, 256, 0, stream>>>(uh, AEh, pred_out, NNODES, BB, NNODES);
  }
  {
    // clusters = sigmoid(userb @ fc2_w^T + fc2_b) : M=128, N=16, K=200 (fp32)
    dim3 grid(1, (BB+63)/64, 1);
    gemm64<2,0,true><<<grid, 256, 0, stream>>>(userb, D_F, fc2_w, D_F, clus_out, NCL,
                                               fc2_b, BB, NCL, D_F, D_F);
  }
}

// Round 4
// 932.956 us; speedup vs baseline: 1.7329x; 1.1194x over previous
//
#include <hip/hip_runtime.h>
#include <hip/hip_bf16.h>
#include <math.h>

// Problem constants (from reference setup_inputs)
#define NNODES 100000
#define INIT_F 100
#define GC1_F  150
#define D_F    200
#define CCH    200
#define BB     128
#define NA_    8
#define EDG    500000
#define NCL    16

#define MROWS  100032   // 1563 * 64, padded row count for MFMA A/B operands

// bf16 K-padded pitches (elements)
#define KP1    128      // gcn1: K=100 -> 128
#define KP2    160      // gcn2: K=150 -> 160
#define KPP    224      // pred: K=200 -> 224
#define FCK    40000    // fc: K (exact multiple of 32)

typedef __attribute__((ext_vector_type(8))) __bf16 bf16x8;
typedef __attribute__((ext_vector_type(4))) float  f32x4;

// ---------------- CSR build ----------------

__global__ void count_deg_k(const int* __restrict__ ei, int* __restrict__ deg, int E){
  int e = blockIdx.x*256 + threadIdx.x;
  if (e >= E) return;
  atomicAdd(&deg[ei[e]], 1);
  atomicAdd(&deg[ei[E+e]], 1);
}

__global__ void scan_block_k(const int* __restrict__ deg, int* __restrict__ incl,
                             int* __restrict__ bsum, int n){
  __shared__ int s[256];
  int t = threadIdx.x;
  int i = blockIdx.x*256 + t;
  int v = (i < n) ? deg[i] : 0;
  s[t] = v; __syncthreads();
  for (int off = 1; off < 256; off <<= 1){
    int x = (t >= off) ? s[t-off] : 0;
    __syncthreads();
    s[t] += x; __syncthreads();
  }
  if (i < n) incl[i] = s[t];
  if (t == 255) bsum[blockIdx.x] = s[255];
}

__global__ void scan_tot_k(const int* __restrict__ bsum, int* __restrict__ boff, int nb){
  __shared__ int s[512];
  int t = threadIdx.x;
  s[t] = (t < nb) ? bsum[t] : 0; __syncthreads();
  for (int off = 1; off < 512; off <<= 1){
    int x = (t >= off) ? s[t-off] : 0;
    __syncthreads();
    s[t] += x; __syncthreads();
  }
  if (t < nb) boff[t] = s[t] - bsum[t];   // exclusive block offset
}

__global__ void csr_fin_k(const int* __restrict__ incl, const int* __restrict__ deg,
                          const int* __restrict__ boff, int* __restrict__ rowptr,
                          int* __restrict__ cursor, int n, int total){
  int i = blockIdx.x*256 + threadIdx.x;
  if (i < n){
    int ex = incl[i] - deg[i] + boff[i >> 8];
    rowptr[i] = ex; cursor[i] = ex;
  }
  if (i == 0) rowptr[n] = total;
}

__global__ void fill_k(const int* __restrict__ ei, const int* __restrict__ erel,
                       int* __restrict__ cursor, int* __restrict__ adj,
                       int* __restrict__ arel, int E){
  int e = blockIdx.x*256 + threadIdx.x;
  if (e >= E) return;
  int r = ei[e], c = ei[E+e], rl = erel[e];
  int p = atomicAdd(&cursor[r], 1); adj[p] = c; arel[p] = rl;
  int q = atomicAdd(&cursor[c], 1); adj[q] = r; arel[q] = rl;
}

// ---------------- GCN gather: fp32 float4 in, bf16 out ----------------

template<int PIN4, int NRD, int WL, int PHO, int F>
__global__ __launch_bounds__(256) void gcn_gather_b(
    const float4* __restrict__ sup, const int* __restrict__ rowptr,
    const int* __restrict__ adj, const int* __restrict__ arel,
    const float* __restrict__ alpha, const float* __restrict__ gb,
    const float* __restrict__ bng, const float* __restrict__ bnb,
    __bf16* __restrict__ outH)
{
  int wave = threadIdx.x >> 6;
  int lane = threadIdx.x & 63;
  int v = blockIdx.x*4 + wave;
  if (v >= NNODES) return;
  int s = rowptr[v], e = rowptr[v+1];
  bool act = lane < NRD;
  float4 acc = make_float4(0.f,0.f,0.f,0.f);
  int j = s;
  for (; j + 4 <= e; j += 4){
    int u0 = adj[j], u1 = adj[j+1], u2 = adj[j+2], u3 = adj[j+3];
    float w0 = alpha[arel[j]],   w1 = alpha[arel[j+1]];
    float w2 = alpha[arel[j+2]], w3 = alpha[arel[j+3]];
    if (act){
      float4 a = sup[(long)u0*PIN4 + lane];
      float4 b = sup[(long)u1*PIN4 + lane];
      float4 c = sup[(long)u2*PIN4 + lane];
      float4 d = sup[(long)u3*PIN4 + lane];
      acc.x += w0*a.x + w1*b.x + w2*c.x + w3*d.x;
      acc.y += w0*a.y + w1*b.y + w2*c.y + w3*d.y;
      acc.z += w0*a.z + w1*b.z + w2*c.z + w3*d.z;
      acc.w += w0*a.w + w1*b.w + w2*c.w + w3*d.w;
    }
  }
  for (; j < e; j++){
    int u = adj[j];
    float w = alpha[arel[j]];
    if (act){
      float4 a = sup[(long)u*PIN4 + lane];
      acc.x += w*a.x; acc.y += w*a.y; acc.z += w*a.z; acc.w += w*a.w;
    }
  }
  if (lane < WL){
    const float inv = rsqrtf(1.0f + 1e-5f);
    float r[4] = {acc.x, acc.y, acc.z, acc.w};
    __bf16 ob[4] __attribute__((aligned(8)));
    int f0 = lane*4;
    #pragma unroll
    for (int c = 0; c < 4; c++){
      int f = f0 + c;
      if (f < F){
        float x = r[c] + gb[f];
        x = x * (bng[f]*inv) + bnb[f];
        ob[c] = (__bf16)tanhf(x);
      } else ob[c] = (__bf16)0.f;
    }
    *reinterpret_cast<uint2*>(outH + (long)v*PHO + lane*4) =
        *reinterpret_cast<const uint2*>(ob);
  }
}

// ---------------- bf16 MFMA GEMM (compile-time K) ----------------
// C[M x N](fp32) = A[M x KP](bf16 row-major) * Bt[N x KP](bf16 row-major, B^T)
// A/B operand: lane l -> free idx = l&15, k = (l>>4)*8 + j
// C/D: col = l&15, row = (l>>4)*4 + reg

template<int KP, int ACT>
__global__ __launch_bounds__(256) void mfma_gemm(
    const __bf16* __restrict__ A, const __bf16* __restrict__ Bt,
    float* __restrict__ C, long ldc, int M, int N)
{
  int w = threadIdx.x >> 6, l = threadIdx.x & 63;
  int m0 = blockIdx.y*64 + w*16;
  int n0 = blockIdx.x*64;
  int ml = l & 15, kq = l >> 4;
  const __bf16* Ap = A  + (long)(m0 + ml)*KP + kq*8;
  const __bf16* Bp = Bt + (long)(n0 + ml)*KP + kq*8;
  f32x4 acc[4] = {};
  #pragma unroll
  for (int k0 = 0; k0 < KP; k0 += 32){
    bf16x8 a = *(const bf16x8*)(Ap + k0);
    #pragma unroll
    for (int t = 0; t < 4; t++){
      bf16x8 b = *(const bf16x8*)(Bp + (long)t*16*KP + k0);
      acc[t] = __builtin_amdgcn_mfma_f32_16x16x32_bf16(a, b, acc[t], 0, 0, 0);
    }
  }
  int mr = m0 + kq*4;
  #pragma unroll
  for (int t = 0; t < 4; t++){
    int gn = n0 + t*16 + ml;
    if (gn >= N) continue;
    #pragma unroll
    for (int r = 0; r < 4; r++){
      int gm = mr + r;
      if (gm < M){
        float x = acc[t][r];
        if (ACT == 2) x = 1.f/(1.f + __expf(-x));
        C[(long)gm*ldc + gn] = x;
      }
    }
  }
}

// ---------------- fc MFMA: split-K, atomic accumulate ----------------
// A[M x FCK], Bt[N' x FCK] (N'=256 padded rows), C[M x N] fp32 += A*Bt^T slice

__global__ __launch_bounds__(256) void mfma_fc_k(
    const __bf16* __restrict__ A, const __bf16* __restrict__ Bt,
    float* __restrict__ C, int M, int N, int klen)
{
  int w = threadIdx.x >> 6, l = threadIdx.x & 63;
  int m0 = blockIdx.y*64 + w*16;
  int n0 = blockIdx.x*64;
  long kb = (long)blockIdx.z * klen;
  int ml = l & 15, kq = l >> 4;
  const __bf16* Ap = A  + (long)(m0 + ml)*FCK + kb + kq*8;
  const __bf16* Bp = Bt + (long)(n0 + ml)*FCK + kb + kq*8;
  f32x4 acc[4] = {};
  #pragma unroll 2
  for (int k0 = 0; k0 < klen; k0 += 32){
    bf16x8 a = *(const bf16x8*)(Ap + k0);
    #pragma unroll
    for (int t = 0; t < 4; t++){
      bf16x8 b = *(const bf16x8*)(Bp + (long)t*16*FCK + k0);
      acc[t] = __builtin_amdgcn_mfma_f32_16x16x32_bf16(a, b, acc[t], 0, 0, 0);
    }
  }
  int mr = m0 + kq*4;
  #pragma unroll
  for (int t = 0; t < 4; t++){
    int gn = n0 + t*16 + ml;
    if (gn >= N) continue;
    #pragma unroll
    for (int r = 0; r < 4; r++){
      int gm = mr + r;
      if (gm < M) atomicAdd(&C[(long)gm*N + gn], acc[t][r]);
    }
  }
}

// ---------------- conversion helpers ----------------

__global__ void conv_a_bf16_k(const float* __restrict__ src, __bf16* __restrict__ dst,
                              int cols, int colsP){
  long r = blockIdx.x;
  for (int j = threadIdx.x; j < colsP; j += blockDim.x)
    dst[r*colsP + j] = (j < cols) ? (__bf16)src[r*cols + j] : (__bf16)0.f;
}

__global__ void transpose_w_k(const float* __restrict__ W, __bf16* __restrict__ Bt,
                              int K, int N, int Kp){
  int n = blockIdx.x;
  for (int k = threadIdx.x; k < Kp; k += blockDim.x){
    float v = (k < K && n < N) ? W[(long)k*N + n] : 0.f;
    Bt[(long)n*Kp + k] = (__bf16)v;
  }
}

// flat fp32 -> bf16 cast, vectorized (n4 = count/4)
__global__ void f32_to_bf16_flat_k(const float4* __restrict__ src,
                                   __bf16* __restrict__ dst, long n4){
  long i = (long)blockIdx.x*256 + threadIdx.x;
  if (i >= n4) return;
  float4 v = src[i];
  __bf16 o[4] __attribute__((aligned(8))) =
      {(__bf16)v.x, (__bf16)v.y, (__bf16)v.z, (__bf16)v.w};
  *reinterpret_cast<uint2*>(dst + i*4) = *reinterpret_cast<const uint2*>(o);
}

// ---------------- small fused kernels ----------------

__global__ void build_s_k(const int* __restrict__ e1, const int* __restrict__ rel,
                          const __bf16* __restrict__ AEh, const float* __restrict__ embrel,
                          const float* __restrict__ g0, const float* __restrict__ b0,
                          float* __restrict__ s){
  int b = blockIdx.x, t = threadIdx.x;
  if (t >= D_F) return;
  const float inv = rsqrtf(1.0f + 1e-5f);
  float ev = (float)AEh[(long)e1[b]*KPP + t];
  s[(b*2+0)*D_F + t] = ev * (g0[0]*inv) + b0[0];
  s[(b*2+1)*D_F + t] = embrel[(long)rel[b]*D_F + t] * (g0[1]*inv) + b0[1];
}

// conv1d(K=5, pad=2, 2 in-ch) + bias + bn1 + relu -> bf16 A operand for fc
__global__ void conv_bn_relu_k(const float* __restrict__ s, const float* __restrict__ cw,
                               const float* __restrict__ cb, const float* __restrict__ g1,
                               const float* __restrict__ b1, __bf16* __restrict__ out){
  __shared__ float sh[2][D_F];
  int b = blockIdx.y, c0 = blockIdx.x*8, t = threadIdx.x;
  if (t < D_F){
    sh[0][t] = s[(b*2+0)*D_F + t];
    sh[1][t] = s[(b*2+1)*D_F + t];
  }
  __syncthreads();
  if (t >= D_F) return;
  const float inv = rsqrtf(1.0f + 1e-5f);
  for (int cc = 0; cc < 8; cc++){
    int c = c0 + cc;
    float sum = cb[c];
    #pragma unroll
    for (int i = 0; i < 2; i++){
      #pragma unroll
      for (int k = 0; k < 5; k++){
        int h = t + k - 2;
        float sv = (h >= 0 && h < D_F) ? sh[i][h] : 0.f;
        sum += sv * cw[(c*2+i)*5 + k];
      }
    }
    float x = sum * (g1[c]*inv) + b1[c];
    out[((long)b*CCH + c)*D_F + t] = (__bf16)fmaxf(x, 0.f);
  }
}

__global__ void fc_fin_k(const float* __restrict__ raw, const float* __restrict__ fb,
                         const float* __restrict__ g, const float* __restrict__ bb,
                         float* __restrict__ x2){
  int i = blockIdx.x*256 + threadIdx.x;
  if (i >= BB*D_F) return;
  int j = i % D_F;
  const float inv = rsqrtf(1.0f + 1e-5f);
  float x = (raw[i] + fb[j]) * (g[j]*inv) + bb[j];
  x2[i] = fmaxf(x, 0.f);
}

__global__ void feats_k(const int* __restrict__ attr, const __bf16* __restrict__ AEh,
                        float* __restrict__ ssum, float* __restrict__ deep){
  int b = blockIdx.x, t = threadIdx.x;
  if (t >= D_F) return;
  float s = 0.f, sq = 0.f;
  #pragma unroll
  for (int a = 0; a < NA_; a++){
    int id = attr[b*NA_ + a];
    float v = (float)AEh[(long)id*KPP + t];
    s += v; sq += v*v;
  }
  ssum[b*D_F + t] = s;
  deep[b*D_F + t] = 0.5f*(s*s - sq);
}

// ---------------- generic 64x64 tiled fp32 GEMM (small shapes only) ----------------

template<int ACT, int MODE, bool BT>
__global__ __launch_bounds__(256) void gemm64(
    const float* __restrict__ A, int lda,
    const float* __restrict__ Bm, int ldb,
    float* __restrict__ Cm, int ldc,
    const float* __restrict__ bias,
    int M, int N, int K, int klen)
{
  __shared__ float As[16][68];
  __shared__ float Bs[16][68];
  int tid = threadIdx.x;
  int tm = tid >> 4, tn = tid & 15;
  int m0 = blockIdx.y*64, n0 = blockIdx.x*64;
  int k0 = blockIdx.z * klen;
  int kend = min(k0 + klen, K);
  float acc[4][4] = {};

  for (int ks = k0; ks < kend; ks += 16){
    #pragma unroll
    for (int i = 0; i < 4; i++){
      int idx = tid + 256*i;
      int m = idx & 63, k = idx >> 6;
      int gm = m0 + m, gk = ks + k;
      As[k][m] = (gm < M && gk < kend) ? A[(long)gm*lda + gk] : 0.f;
    }
    #pragma unroll
    for (int i = 0; i < 4; i++){
      int idx = tid + 256*i;
      int n = idx & 63, k = idx >> 6;
      int gn = n0 + n, gk = ks + k;
      float v = 0.f;
      if (gn < N && gk < kend)
        v = BT ? Bm[(long)gn*ldb + gk] : Bm[(long)gk*ldb + gn];
      Bs[k][n] = v;
    }
    __syncthreads();
    #pragma unroll
    for (int kk = 0; kk < 16; kk++){
      float a[4], b[4];
      #pragma unroll
      for (int i = 0; i < 4; i++) a[i] = As[kk][tm*4+i];
      #pragma unroll
      for (int i = 0; i < 4; i++) b[i] = Bs[kk][tn*4+i];
      #pragma unroll
      for (int i = 0; i < 4; i++)
        #pragma unroll
        for (int j = 0; j < 4; j++)
          acc[i][j] += a[i]*b[j];
    }
    __syncthreads();
  }

  #pragma unroll
  for (int i = 0; i < 4; i++){
    int gm = m0 + tm*4 + i; if (gm >= M) continue;
    #pragma unroll
    for (int j = 0; j < 4; j++){
      int gn = n0 + tn*4 + j; if (gn >= N) continue;
      long co = (long)gm*ldc + gn;
      float x = acc[i][j];
      if (MODE == 3){ atomicAdd(&Cm[co], x); continue; }
      if (MODE == 2) x += Cm[co];
      if (bias) x += bias[gn];
      if (ACT == 1) x = (x >= 0.f) ? x : 0.01f*x;
      else if (ACT == 2) x = 1.f/(1.f + __expf(-x));
      float r = x;
      if (MODE == 1) r = Cm[co] + x;
      Cm[co] = r;
    }
  }
}

// ---------------- launch ----------------

extern "C" void kernel_launch(void* const* d_in, const int* in_sizes, int n_in,
                              void* d_out, int out_size, void* d_ws, size_t ws_size,
                              hipStream_t stream) {
  const int* e1       = (const int*)d_in[0];
  const int* rel      = (const int*)d_in[1];
  const int* attr     = (const int*)d_in[2];
  const int* ei       = (const int*)d_in[4];
  const int* erel     = (const int*)d_in[5];
  const float* emb_e  = (const float*)d_in[6];
  const float* embrel = (const float*)d_in[7];
  const float* alpha1 = (const float*)d_in[8];
  const float* alpha2 = (const float*)d_in[9];
  const float* gc1_W  = (const float*)d_in[10];
  const float* gc1_b  = (const float*)d_in[11];
  const float* gc2_W  = (const float*)d_in[12];
  const float* gc2_b  = (const float*)d_in[13];
  const float* bn3_g  = (const float*)d_in[14];
  const float* bn3_b  = (const float*)d_in[15];
  const float* bn4_g  = (const float*)d_in[16];
  const float* bn4_b  = (const float*)d_in[17];
  const float* bn0_g  = (const float*)d_in[18];
  const float* bn0_b  = (const float*)d_in[19];
  const float* conv_w = (const float*)d_in[20];
  const float* conv_b = (const float*)d_in[21];
  const float* bn1_g  = (const float*)d_in[22];
  const float* bn1_b  = (const float*)d_in[23];
  const float* fc_w   = (const float*)d_in[24];
  const float* fc_b   = (const float*)d_in[25];
  const float* bn2_g  = (const float*)d_in[26];
  const float* bn2_b  = (const float*)d_in[27];
  const float* bi_w   = (const float*)d_in[28];
  const float* bi_b   = (const float*)d_in[29];
  const float* si_w   = (const float*)d_in[30];
  const float* si_b   = (const float*)d_in[31];
  const float* cs_w   = (const float*)d_in[32];
  const float* cs_b   = (const float*)d_in[33];
  const float* fc2_w  = (const float*)d_in[34];
  const float* fc2_b  = (const float*)d_in[35];

  float* pred_out = (float*)d_out;                       // 128 x 100000
  float* clus_out = (float*)d_out + (long)BB*NNODES;     // 128 x 16

  char* w = (char*)d_ws;
  size_t off = 0;
  auto alloc = [&](size_t bytes) -> void* {
    off = (off + 255) & ~(size_t)255;
    void* p = w + off;
    off += bytes;
    return p;
  };
  // R1: S1 (100000 x 152 fp32 = 60.8MB), later AEh (MROWS x 224 bf16 = 44.8MB)
  void* R1 = alloc((size_t)NNODES*152*4);
  // R2: emb_h (MROWS x 128 bf16), then S2 (100000 x 200 fp32 = 80MB), then fcBt (256 x 40000 bf16 = 20.5MB)
  void* R2 = alloc((size_t)NNODES*D_F*4);
  // R3: H1h (MROWS x 160 bf16 = 32MB), later convout bf16 (128 x 40000 = 10.24MB)
  void* R3 = alloc((size_t)MROWS*KP2*2);

  int* deg    = (int*)alloc((size_t)NNODES*4);
  int* incl   = (int*)alloc((size_t)NNODES*4);
  int* bsum   = (int*)alloc(512*4);
  int* boff   = (int*)alloc(512*4);
  int* rowptr = (int*)alloc((size_t)(NNODES+1)*4);
  int* cursor = (int*)alloc((size_t)NNODES*4);
  int* adj    = (int*)alloc((size_t)2*EDG*4);
  int* arel   = (int*)alloc((size_t)2*EDG*4);
  __bf16* Bt1 = (__bf16*)alloc((size_t)192*KP1*2);
  __bf16* Bt2 = (__bf16*)alloc((size_t)256*KP2*2);
  __bf16* uh  = (__bf16*)alloc((size_t)BB*KPP*2);
  float* sbuf   = (float*)alloc((size_t)BB*2*D_F*4);
  float* x2raw  = (float*)alloc((size_t)BB*D_F*4);
  float* x2     = (float*)alloc((size_t)BB*D_F*4);
  float* ssum   = (float*)alloc((size_t)BB*D_F*4);
  float* deep   = (float*)alloc((size_t)BB*D_F*4);
  float* nfm    = (float*)alloc((size_t)BB*D_F*4);
  float* userb  = (float*)alloc((size_t)BB*D_F*4);

  float*  S1    = (float*)R1;     // pitch 152
  __bf16* AEh   = (__bf16*)R1;    // pitch 224
  __bf16* emb_h = (__bf16*)R2;    // pitch 128
  float*  S2    = (float*)R2;     // pitch 200
  __bf16* fcBt  = (__bf16*)R2;    // 256 x 40000 (S2 dead after gather2)
  __bf16* H1h   = (__bf16*)R3;    // pitch 160
  __bf16* convout = (__bf16*)R3;  // 128 x 40000 (H1h dead after gcn2 gemm)

  const int EB = (EDG + 255)/256;
  const int NB = (NNODES + 255)/256;
  const int GGB = (NNODES + 3)/4;
  const int MT = MROWS/64;        // 1563

  // ---- CSR build ----
  hipMemsetAsync(deg, 0, (size_t)NNODES*4, stream);
  hipMemsetAsync(x2raw, 0, (size_t)BB*D_F*4, stream);
  count_deg_k<<<EB, 256, 0, stream>>>(ei, deg, EDG);
  scan_block_k<<<NB, 256, 0, stream>>>(deg, incl, bsum, NNODES);
  scan_tot_k<<<1, 512, 0, stream>>>(bsum, boff, NB);
  csr_fin_k<<<NB, 256, 0, stream>>>(incl, deg, boff, rowptr, cursor, NNODES, 2*EDG);
  fill_k<<<EB, 256, 0, stream>>>(ei, erel, cursor, adj, arel, EDG);

  // ---- operand prep ----
  conv_a_bf16_k<<<NNODES, 128, 0, stream>>>(emb_e, emb_h, INIT_F, KP1);
  transpose_w_k<<<192, 128, 0, stream>>>(gc1_W, Bt1, INIT_F, GC1_F, KP1);
  transpose_w_k<<<256, 128, 0, stream>>>(gc2_W, Bt2, GC1_F, D_F, KP2);

  // ---- GCN layer 1: S1 = emb_h @ gc1_W  (M=1e5, N=150, K=100) ----
  {
    dim3 grid(3, MT);
    mfma_gemm<KP1,0><<<grid, 256, 0, stream>>>(emb_h, Bt1, S1, 152, NNODES, GC1_F);
  }
  gcn_gather_b<38,38,40,KP2,GC1_F><<<GGB, 256, 0, stream>>>(
      (const float4*)S1, rowptr, adj, arel, alpha1, gc1_b, bn3_g, bn3_b, H1h);

  // ---- GCN layer 2: S2 = H1h @ gc2_W  (M=1e5, N=200, K=150) ----
  {
    dim3 grid(4, MT);
    mfma_gemm<KP2,0><<<grid, 256, 0, stream>>>(H1h, Bt2, S2, D_F, NNODES, D_F);
  }
  gcn_gather_b<50,50,56,KPP,D_F><<<GGB, 256, 0, stream>>>(
      (const float4*)S2, rowptr, adj, arel, alpha2, gc2_b, bn4_g, bn4_b, AEh);

  // ---- conv head (convout emitted as bf16 fc A-operand) ----
  build_s_k<<<BB, 256, 0, stream>>>(e1, rel, AEh, embrel, bn0_g, bn0_b, sbuf);
  {
    dim3 grid(CCH/8, BB);
    conv_bn_relu_k<<<grid, 256, 0, stream>>>(sbuf, conv_w, conv_b, bn1_g, bn1_b, convout);
  }
  // fc_w [200 x 40000] row-major == Bt layout; cast to bf16 (S2 region now dead)
  hipMemsetAsync(fcBt + (size_t)200*FCK, 0, (size_t)56*FCK*2, stream);
  {
    long n4 = (long)D_F*FCK/4;   // 2,000,000
    f32_to_bf16_flat_k<<<(int)((n4 + 255)/256), 256, 0, stream>>>(
        (const float4*)fc_w, fcBt, n4);
  }
  // fc: 128 x 200 = convout[128 x 40000] @ fcBt^T, split-K z=50, atomic fp32
  {
    dim3 grid(4, 2, 50);
    mfma_fc_k<<<grid, 256, 0, stream>>>(convout, fcBt, x2raw, BB, D_F, FCK/50);
  }
  fc_fin_k<<<(BB*D_F+255)/256, 256, 0, stream>>>(x2raw, fc_b, bn2_g, bn2_b, x2);

  // ---- NFM branch ----
  feats_k<<<BB, 256, 0, stream>>>(attr, AEh, ssum, deep);
  {
    dim3 grid((D_F+63)/64, (BB+63)/64, 1);
    gemm64<1,0,true><<<grid, 256, 0, stream>>>(deep, D_F, bi_w, D_F, nfm, D_F,
                                               bi_b, BB, D_F, D_F, D_F);
    gemm64<1,1,true><<<grid, 256, 0, stream>>>(ssum, D_F, si_w, D_F, nfm, D_F,
                                               si_b, BB, D_F, D_F, D_F);
    gemm64<0,0,true><<<grid, 256, 0, stream>>>(nfm, D_F, cs_w, 2*D_F, userb, D_F,
                                               nullptr, BB, D_F, D_F, D_F);
    gemm64<1,2,true><<<grid, 256, 0, stream>>>(x2, D_F, cs_w + D_F, 2*D_F, userb, D_F,
                                               cs_b, BB, D_F, D_F, D_F);
  }

  // ---- outputs ----
  conv_a_bf16_k<<<BB, 256, 0, stream>>>(userb, uh, D_F, KPP);
  {
    // pred = sigmoid(uh @ AEh^T) : M=128, N=100000, K=200(->224)
    dim3 grid(MT, 2);
    mfma_gemm<KPP,2><<<grid, 256, 0, stream>>>(uh, AEh, pred_out, NNODES, BB, NNODES);
  }
  {
    // clusters = sigmoid(userb @ fc2_w^T + fc2_b) : M=128, N=16, K=200 (fp32)
    dim3 grid(1, (BB+63)/64, 1);
    gemm64<2,0,true><<<grid, 256, 0, stream>>>(userb, D_F, fc2_w, D_F, clus_out, NCL,
                                               fc2_b, BB, NCL, D_F, D_F);
  }
}

// Round 5
// 853.244 us; speedup vs baseline: 1.8948x; 1.0934x over previous
//
#include <hip/hip_runtime.h>
#include <hip/hip_bf16.h>
#include <math.h>

// Problem constants (from reference setup_inputs)
#define NNODES 100000
#define INIT_F 100
#define GC1_F  150
#define D_F    200
#define CCH    200
#define BB     128
#define NA_    8
#define EDG    500000
#define NCL    16

#define MROWS  100032   // 1563 * 64, padded row count for MFMA A operands

// bf16 K-padded pitches (elements)
#define KP1    128      // layer1 input features: 100 -> 128
#define KP2    160      // layer2 input features: 150 -> 160
#define KPP    224      // head features: 200 -> 224
#define FCK    40000    // fc K

typedef __attribute__((ext_vector_type(8))) __bf16 bf16x8;
typedef __attribute__((ext_vector_type(4))) float  f32x4;

// ---------------- CSR build ----------------

__global__ void count_deg_k(const int* __restrict__ ei, int* __restrict__ deg, int E){
  int e = blockIdx.x*256 + threadIdx.x;
  if (e >= E) return;
  atomicAdd(&deg[ei[e]], 1);
  atomicAdd(&deg[ei[E+e]], 1);
}

__global__ void scan_block_k(const int* __restrict__ deg, int* __restrict__ incl,
                             int* __restrict__ bsum, int n){
  __shared__ int s[256];
  int t = threadIdx.x;
  int i = blockIdx.x*256 + t;
  int v = (i < n) ? deg[i] : 0;
  s[t] = v; __syncthreads();
  for (int off = 1; off < 256; off <<= 1){
    int x = (t >= off) ? s[t-off] : 0;
    __syncthreads();
    s[t] += x; __syncthreads();
  }
  if (i < n) incl[i] = s[t];
  if (t == 255) bsum[blockIdx.x] = s[255];
}

__global__ void scan_tot_k(const int* __restrict__ bsum, int* __restrict__ boff, int nb){
  __shared__ int s[512];
  int t = threadIdx.x;
  s[t] = (t < nb) ? bsum[t] : 0; __syncthreads();
  for (int off = 1; off < 512; off <<= 1){
    int x = (t >= off) ? s[t-off] : 0;
    __syncthreads();
    s[t] += x; __syncthreads();
  }
  if (t < nb) boff[t] = s[t] - bsum[t];   // exclusive block offset
}

__global__ void csr_fin_k(const int* __restrict__ incl, const int* __restrict__ deg,
                          const int* __restrict__ boff, int* __restrict__ rowptr,
                          int* __restrict__ cursor, int n, int total){
  int i = blockIdx.x*256 + threadIdx.x;
  if (i < n){
    int ex = incl[i] - deg[i] + boff[i >> 8];
    rowptr[i] = ex; cursor[i] = ex;
  }
  if (i == 0) rowptr[n] = total;
}

__global__ void fill_k(const int* __restrict__ ei, const int* __restrict__ erel,
                       int* __restrict__ cursor, int* __restrict__ adj,
                       int* __restrict__ arel, int E){
  int e = blockIdx.x*256 + threadIdx.x;
  if (e >= E) return;
  int r = ei[e], c = ei[E+e], rl = erel[e];
  int p = atomicAdd(&cursor[r], 1); adj[p] = c; arel[p] = rl;
  int q = atomicAdd(&cursor[c], 1); adj[q] = r; arel[q] = rl;
}

// ---------------- bf16 pre-GEMM gather: Z[v] = sum_j alpha[rel_j] * X[u_j] ----------------
// Aggregation commutes with the GCN GEMM (linear over rows), so we gather the
// NARROW input features in bf16 (208/320 B per row vs 608/800 B fp32 post-GEMM).
// One wave per node, LN lanes x bf16x8; 4 independent row loads in flight.
// X pad cols are zero -> Z pad cols stay zero exactly.

template<int LN, int PIN>
__global__ __launch_bounds__(256) void gather_h(
    const __bf16* __restrict__ X, const int* __restrict__ rowptr,
    const int* __restrict__ adj, const int* __restrict__ arel,
    const float* __restrict__ alpha, __bf16* __restrict__ Z)
{
  int wave = threadIdx.x >> 6;
  int lane = threadIdx.x & 63;
  int v = blockIdx.x*4 + wave;
  if (v >= NNODES) return;
  int s = rowptr[v], e = rowptr[v+1];
  bool act = lane < LN;
  float acc[8] = {};
  int j = s;
  for (; j + 4 <= e; j += 4){
    int u0 = adj[j], u1 = adj[j+1], u2 = adj[j+2], u3 = adj[j+3];
    float w0 = alpha[arel[j]],   w1 = alpha[arel[j+1]];
    float w2 = alpha[arel[j+2]], w3 = alpha[arel[j+3]];
    if (act){
      bf16x8 a = *(const bf16x8*)(X + (long)u0*PIN + lane*8);
      bf16x8 b = *(const bf16x8*)(X + (long)u1*PIN + lane*8);
      bf16x8 c = *(const bf16x8*)(X + (long)u2*PIN + lane*8);
      bf16x8 d = *(const bf16x8*)(X + (long)u3*PIN + lane*8);
      #pragma unroll
      for (int i = 0; i < 8; i++)
        acc[i] += w0*(float)a[i] + w1*(float)b[i] + w2*(float)c[i] + w3*(float)d[i];
    }
  }
  for (; j < e; j++){
    int u = adj[j];
    float w = alpha[arel[j]];
    if (act){
      bf16x8 a = *(const bf16x8*)(X + (long)u*PIN + lane*8);
      #pragma unroll
      for (int i = 0; i < 8; i++) acc[i] += w*(float)a[i];
    }
  }
  if (act){
    bf16x8 o;
    #pragma unroll
    for (int i = 0; i < 8; i++) o[i] = (__bf16)acc[i];
    *(bf16x8*)(Z + (long)v*PIN + lane*8) = o;
  }
}

// ---------------- GCN MFMA GEMM with fused bias+bn+tanh, bf16 out ----------------
// C[M x PHO](bf16) = tanh(bn(Z[M x KP] @ W + gb)); pad cols [N,PHO) written 0.
// A/B operand: lane l -> free idx = l&15, k = (l>>4)*8 + j ;  C/D: col=l&15, row=(l>>4)*4+reg

template<int KP, int PHO>
__global__ __launch_bounds__(256) void mfma_gcn(
    const __bf16* __restrict__ A, const __bf16* __restrict__ Bt,
    __bf16* __restrict__ C,
    const float* __restrict__ gb, const float* __restrict__ bng,
    const float* __restrict__ bnb, int M, int N)
{
  int w = threadIdx.x >> 6, l = threadIdx.x & 63;
  int m0 = blockIdx.y*64 + w*16;
  int n0 = blockIdx.x*64;
  int ml = l & 15, kq = l >> 4;
  const __bf16* Ap = A  + (long)(m0 + ml)*KP + kq*8;
  const __bf16* Bp = Bt + (long)(n0 + ml)*KP + kq*8;
  f32x4 acc[4] = {};
  #pragma unroll
  for (int k0 = 0; k0 < KP; k0 += 32){
    bf16x8 a = *(const bf16x8*)(Ap + k0);
    #pragma unroll
    for (int t = 0; t < 4; t++){
      bf16x8 b = *(const bf16x8*)(Bp + (long)t*16*KP + k0);
      acc[t] = __builtin_amdgcn_mfma_f32_16x16x32_bf16(a, b, acc[t], 0, 0, 0);
    }
  }
  const float inv = rsqrtf(1.0f + 1e-5f);
  int mr = m0 + kq*4;
  #pragma unroll
  for (int t = 0; t < 4; t++){
    int gn = n0 + t*16 + ml;
    if (gn >= PHO) continue;
    bool real = gn < N;
    float gbb = real ? gb[gn] : 0.f;
    float sc  = real ? bng[gn]*inv : 0.f;
    float bb_ = real ? bnb[gn] : 0.f;
    #pragma unroll
    for (int r = 0; r < 4; r++){
      int gm = mr + r;
      if (gm < M){
        float x = real ? tanhf((acc[t][r] + gbb)*sc + bb_) : 0.f;
        C[(long)gm*PHO + gn] = (__bf16)x;
      }
    }
  }
}

// ---------------- bf16 MFMA GEMM, fp32 out (pred) ----------------

template<int KP, int ACT>
__global__ __launch_bounds__(256) void mfma_gemm(
    const __bf16* __restrict__ A, const __bf16* __restrict__ Bt,
    float* __restrict__ C, long ldc, int M, int N)
{
  int w = threadIdx.x >> 6, l = threadIdx.x & 63;
  int m0 = blockIdx.y*64 + w*16;
  int n0 = blockIdx.x*64;
  int ml = l & 15, kq = l >> 4;
  const __bf16* Ap = A  + (long)(m0 + ml)*KP + kq*8;
  const __bf16* Bp = Bt + (long)(n0 + ml)*KP + kq*8;
  f32x4 acc[4] = {};
  #pragma unroll
  for (int k0 = 0; k0 < KP; k0 += 32){
    bf16x8 a = *(const bf16x8*)(Ap + k0);
    #pragma unroll
    for (int t = 0; t < 4; t++){
      bf16x8 b = *(const bf16x8*)(Bp + (long)t*16*KP + k0);
      acc[t] = __builtin_amdgcn_mfma_f32_16x16x32_bf16(a, b, acc[t], 0, 0, 0);
    }
  }
  int mr = m0 + kq*4;
  #pragma unroll
  for (int t = 0; t < 4; t++){
    int gn = n0 + t*16 + ml;
    if (gn >= N) continue;
    #pragma unroll
    for (int r = 0; r < 4; r++){
      int gm = mr + r;
      if (gm < M){
        float x = acc[t][r];
        if (ACT == 2) x = 1.f/(1.f + __expf(-x));
        C[(long)gm*ldc + gn] = x;
      }
    }
  }
}

// ---------------- fc MFMA: split-K, atomic accumulate ----------------

__global__ __launch_bounds__(256) void mfma_fc_k(
    const __bf16* __restrict__ A, const __bf16* __restrict__ Bt,
    float* __restrict__ C, int M, int N, int klen)
{
  int w = threadIdx.x >> 6, l = threadIdx.x & 63;
  int m0 = blockIdx.y*64 + w*16;
  int n0 = blockIdx.x*64;
  long kb = (long)blockIdx.z * klen;
  int ml = l & 15, kq = l >> 4;
  const __bf16* Ap = A  + (long)(m0 + ml)*FCK + kb + kq*8;
  const __bf16* Bp = Bt + (long)(n0 + ml)*FCK + kb + kq*8;
  f32x4 acc[4] = {};
  #pragma unroll 2
  for (int k0 = 0; k0 < klen; k0 += 32){
    bf16x8 a = *(const bf16x8*)(Ap + k0);
    #pragma unroll
    for (int t = 0; t < 4; t++){
      bf16x8 b = *(const bf16x8*)(Bp + (long)t*16*FCK + k0);
      acc[t] = __builtin_amdgcn_mfma_f32_16x16x32_bf16(a, b, acc[t], 0, 0, 0);
    }
  }
  int mr = m0 + kq*4;
  #pragma unroll
  for (int t = 0; t < 4; t++){
    int gn = n0 + t*16 + ml;
    if (gn >= N) continue;
    #pragma unroll
    for (int r = 0; r < 4; r++){
      int gm = mr + r;
      if (gm < M) atomicAdd(&C[(long)gm*N + gn], acc[t][r]);
    }
  }
}

// ---------------- conversion helpers ----------------

__global__ void conv_a_bf16_k(const float* __restrict__ src, __bf16* __restrict__ dst,
                              int cols, int colsP){
  long r = blockIdx.x;
  for (int j = threadIdx.x; j < colsP; j += blockDim.x)
    dst[r*colsP + j] = (j < cols) ? (__bf16)src[r*cols + j] : (__bf16)0.f;
}

__global__ void transpose_w_k(const float* __restrict__ W, __bf16* __restrict__ Bt,
                              int K, int N, int Kp){
  int n = blockIdx.x;
  for (int k = threadIdx.x; k < Kp; k += blockDim.x){
    float v = (k < K && n < N) ? W[(long)k*N + n] : 0.f;
    Bt[(long)n*Kp + k] = (__bf16)v;
  }
}

__global__ void f32_to_bf16_flat_k(const float4* __restrict__ src,
                                   __bf16* __restrict__ dst, long n4){
  long i = (long)blockIdx.x*256 + threadIdx.x;
  if (i >= n4) return;
  float4 v = src[i];
  __bf16 o[4] __attribute__((aligned(8))) =
      {(__bf16)v.x, (__bf16)v.y, (__bf16)v.z, (__bf16)v.w};
  *reinterpret_cast<uint2*>(dst + i*4) = *reinterpret_cast<const uint2*>(o);
}

// ---------------- small fused kernels ----------------

__global__ void build_s_k(const int* __restrict__ e1, const int* __restrict__ rel,
                          const __bf16* __restrict__ AEh, const float* __restrict__ embrel,
                          const float* __restrict__ g0, const float* __restrict__ b0,
                          float* __restrict__ s){
  int b = blockIdx.x, t = threadIdx.x;
  if (t >= D_F) return;
  const float inv = rsqrtf(1.0f + 1e-5f);
  float ev = (float)AEh[(long)e1[b]*KPP + t];
  s[(b*2+0)*D_F + t] = ev * (g0[0]*inv) + b0[0];
  s[(b*2+1)*D_F + t] = embrel[(long)rel[b]*D_F + t] * (g0[1]*inv) + b0[1];
}

__global__ void conv_bn_relu_k(const float* __restrict__ s, const float* __restrict__ cw,
                               const float* __restrict__ cb, const float* __restrict__ g1,
                               const float* __restrict__ b1, __bf16* __restrict__ out){
  __shared__ float sh[2][D_F];
  int b = blockIdx.y, c0 = blockIdx.x*8, t = threadIdx.x;
  if (t < D_F){
    sh[0][t] = s[(b*2+0)*D_F + t];
    sh[1][t] = s[(b*2+1)*D_F + t];
  }
  __syncthreads();
  if (t >= D_F) return;
  const float inv = rsqrtf(1.0f + 1e-5f);
  for (int cc = 0; cc < 8; cc++){
    int c = c0 + cc;
    float sum = cb[c];
    #pragma unroll
    for (int i = 0; i < 2; i++){
      #pragma unroll
      for (int k = 0; k < 5; k++){
        int h = t + k - 2;
        float sv = (h >= 0 && h < D_F) ? sh[i][h] : 0.f;
        sum += sv * cw[(c*2+i)*5 + k];
      }
    }
    float x = sum * (g1[c]*inv) + b1[c];
    out[((long)b*CCH + c)*D_F + t] = (__bf16)fmaxf(x, 0.f);
  }
}

__global__ void fc_fin_k(const float* __restrict__ raw, const float* __restrict__ fb,
                         const float* __restrict__ g, const float* __restrict__ bb,
                         float* __restrict__ x2){
  int i = blockIdx.x*256 + threadIdx.x;
  if (i >= BB*D_F) return;
  int j = i % D_F;
  const float inv = rsqrtf(1.0f + 1e-5f);
  float x = (raw[i] + fb[j]) * (g[j]*inv) + bb[j];
  x2[i] = fmaxf(x, 0.f);
}

__global__ void feats_k(const int* __restrict__ attr, const __bf16* __restrict__ AEh,
                        float* __restrict__ ssum, float* __restrict__ deep){
  int b = blockIdx.x, t = threadIdx.x;
  if (t >= D_F) return;
  float s = 0.f, sq = 0.f;
  #pragma unroll
  for (int a = 0; a < NA_; a++){
    int id = attr[b*NA_ + a];
    float v = (float)AEh[(long)id*KPP + t];
    s += v; sq += v*v;
  }
  ssum[b*D_F + t] = s;
  deep[b*D_F + t] = 0.5f*(s*s - sq);
}

// ---------------- generic 64x64 tiled fp32 GEMM (small shapes only) ----------------

template<int ACT, int MODE, bool BT>
__global__ __launch_bounds__(256) void gemm64(
    const float* __restrict__ A, int lda,
    const float* __restrict__ Bm, int ldb,
    float* __restrict__ Cm, int ldc,
    const float* __restrict__ bias,
    int M, int N, int K, int klen)
{
  __shared__ float As[16][68];
  __shared__ float Bs[16][68];
  int tid = threadIdx.x;
  int tm = tid >> 4, tn = tid & 15;
  int m0 = blockIdx.y*64, n0 = blockIdx.x*64;
  int k0 = blockIdx.z * klen;
  int kend = min(k0 + klen, K);
  float acc[4][4] = {};

  for (int ks = k0; ks < kend; ks += 16){
    #pragma unroll
    for (int i = 0; i < 4; i++){
      int idx = tid + 256*i;
      int m = idx & 63, k = idx >> 6;
      int gm = m0 + m, gk = ks + k;
      As[k][m] = (gm < M && gk < kend) ? A[(long)gm*lda + gk] : 0.f;
    }
    #pragma unroll
    for (int i = 0; i < 4; i++){
      int idx = tid + 256*i;
      int n = idx & 63, k = idx >> 6;
      int gn = n0 + n, gk = ks + k;
      float v = 0.f;
      if (gn < N && gk < kend)
        v = BT ? Bm[(long)gn*ldb + gk] : Bm[(long)gk*ldb + gn];
      Bs[k][n] = v;
    }
    __syncthreads();
    #pragma unroll
    for (int kk = 0; kk < 16; kk++){
      float a[4], b[4];
      #pragma unroll
      for (int i = 0; i < 4; i++) a[i] = As[kk][tm*4+i];
      #pragma unroll
      for (int i = 0; i < 4; i++) b[i] = Bs[kk][tn*4+i];
      #pragma unroll
      for (int i = 0; i < 4; i++)
        #pragma unroll
        for (int j = 0; j < 4; j++)
          acc[i][j] += a[i]*b[j];
    }
    __syncthreads();
  }

  #pragma unroll
  for (int i = 0; i < 4; i++){
    int gm = m0 + tm*4 + i; if (gm >= M) continue;
    #pragma unroll
    for (int j = 0; j < 4; j++){
      int gn = n0 + tn*4 + j; if (gn >= N) continue;
      long co = (long)gm*ldc + gn;
      float x = acc[i][j];
      if (MODE == 3){ atomicAdd(&Cm[co], x); continue; }
      if (MODE == 2) x += Cm[co];
      if (bias) x += bias[gn];
      if (ACT == 1) x = (x >= 0.f) ? x : 0.01f*x;
      else if (ACT == 2) x = 1.f/(1.f + __expf(-x));
      float r = x;
      if (MODE == 1) r = Cm[co] + x;
      Cm[co] = r;
    }
  }
}

// ---------------- launch ----------------

extern "C" void kernel_launch(void* const* d_in, const int* in_sizes, int n_in,
                              void* d_out, int out_size, void* d_ws, size_t ws_size,
                              hipStream_t stream) {
  const int* e1       = (const int*)d_in[0];
  const int* rel      = (const int*)d_in[1];
  const int* attr     = (const int*)d_in[2];
  const int* ei       = (const int*)d_in[4];
  const int* erel     = (const int*)d_in[5];
  const float* emb_e  = (const float*)d_in[6];
  const float* embrel = (const float*)d_in[7];
  const float* alpha1 = (const float*)d_in[8];
  const float* alpha2 = (const float*)d_in[9];
  const float* gc1_W  = (const float*)d_in[10];
  const float* gc1_b  = (const float*)d_in[11];
  const float* gc2_W  = (const float*)d_in[12];
  const float* gc2_b  = (const float*)d_in[13];
  const float* bn3_g  = (const float*)d_in[14];
  const float* bn3_b  = (const float*)d_in[15];
  const float* bn4_g  = (const float*)d_in[16];
  const float* bn4_b  = (const float*)d_in[17];
  const float* bn0_g  = (const float*)d_in[18];
  const float* bn0_b  = (const float*)d_in[19];
  const float* conv_w = (const float*)d_in[20];
  const float* conv_b = (const float*)d_in[21];
  const float* bn1_g  = (const float*)d_in[22];
  const float* bn1_b  = (const float*)d_in[23];
  const float* fc_w   = (const float*)d_in[24];
  const float* fc_b   = (const float*)d_in[25];
  const float* bn2_g  = (const float*)d_in[26];
  const float* bn2_b  = (const float*)d_in[27];
  const float* bi_w   = (const float*)d_in[28];
  const float* bi_b   = (const float*)d_in[29];
  const float* si_w   = (const float*)d_in[30];
  const float* si_b   = (const float*)d_in[31];
  const float* cs_w   = (const float*)d_in[32];
  const float* cs_b   = (const float*)d_in[33];
  const float* fc2_w  = (const float*)d_in[34];
  const float* fc2_b  = (const float*)d_in[35];

  float* pred_out = (float*)d_out;                       // 128 x 100000
  float* clus_out = (float*)d_out + (long)BB*NNODES;     // 128 x 16

  char* w = (char*)d_ws;
  size_t off = 0;
  auto alloc = [&](size_t bytes) -> void* {
    off = (off + 255) & ~(size_t)255;
    void* p = w + off;
    off += bytes;
    return p;
  };
  __bf16* AEh  = (__bf16*)alloc((size_t)MROWS*KPP*2);   // 44.8 MB, final embeddings
  void* bufA   = alloc((size_t)MROWS*KP1*2);            // emb_h, later fcBt (20.5MB<25.6MB)
  void* bufB   = alloc((size_t)MROWS*KP1*2);            // Z1, later convout (10.3MB<25.6MB)
  __bf16* H1h  = (__bf16*)alloc((size_t)MROWS*KP2*2);   // 32 MB
  __bf16* Z2   = (__bf16*)alloc((size_t)MROWS*KP2*2);   // 32 MB

  int* deg    = (int*)alloc((size_t)NNODES*4);
  int* incl   = (int*)alloc((size_t)NNODES*4);
  int* bsum   = (int*)alloc(512*4);
  int* boff   = (int*)alloc(512*4);
  int* rowptr = (int*)alloc((size_t)(NNODES+1)*4);
  int* cursor = (int*)alloc((size_t)NNODES*4);
  int* adj    = (int*)alloc((size_t)2*EDG*4);
  int* arel   = (int*)alloc((size_t)2*EDG*4);
  __bf16* Bt1 = (__bf16*)alloc((size_t)192*KP1*2);
  __bf16* Bt2 = (__bf16*)alloc((size_t)256*KP2*2);
  __bf16* uh  = (__bf16*)alloc((size_t)BB*KPP*2);
  float* sbuf   = (float*)alloc((size_t)BB*2*D_F*4);
  float* x2raw  = (float*)alloc((size_t)BB*D_F*4);
  float* x2     = (float*)alloc((size_t)BB*D_F*4);
  float* ssum   = (float*)alloc((size_t)BB*D_F*4);
  float* deep   = (float*)alloc((size_t)BB*D_F*4);
  float* nfm    = (float*)alloc((size_t)BB*D_F*4);
  float* userb  = (float*)alloc((size_t)BB*D_F*4);

  __bf16* emb_h   = (__bf16*)bufA;   // pitch 128
  __bf16* fcBt    = (__bf16*)bufA;   // 256 x 40000 (emb_h dead after gather1)
  __bf16* Z1      = (__bf16*)bufB;   // pitch 128
  __bf16* convout = (__bf16*)bufB;   // 128 x 40000 (Z1 dead after GEMM1)

  const int EB = (EDG + 255)/256;
  const int NB = (NNODES + 255)/256;
  const int GGB = (NNODES + 3)/4;
  const int MT = MROWS/64;        // 1563

  // ---- CSR build ----
  hipMemsetAsync(deg, 0, (size_t)NNODES*4, stream);
  hipMemsetAsync(x2raw, 0, (size_t)BB*D_F*4, stream);
  count_deg_k<<<EB, 256, 0, stream>>>(ei, deg, EDG);
  scan_block_k<<<NB, 256, 0, stream>>>(deg, incl, bsum, NNODES);
  scan_tot_k<<<1, 512, 0, stream>>>(bsum, boff, NB);
  csr_fin_k<<<NB, 256, 0, stream>>>(incl, deg, boff, rowptr, cursor, NNODES, 2*EDG);
  fill_k<<<EB, 256, 0, stream>>>(ei, erel, cursor, adj, arel, EDG);

  // ---- operand prep ----
  conv_a_bf16_k<<<NNODES, 128, 0, stream>>>(emb_e, emb_h, INIT_F, KP1);
  transpose_w_k<<<192, 128, 0, stream>>>(gc1_W, Bt1, INIT_F, GC1_F, KP1);
  transpose_w_k<<<256, 128, 0, stream>>>(gc2_W, Bt2, GC1_F, D_F, KP2);

  // ---- GCN layer 1: Z1 = agg(emb_h); H1h = tanh(bn3(Z1@W1 + b1)) ----
  gather_h<16,KP1><<<GGB, 256, 0, stream>>>(emb_h, rowptr, adj, arel, alpha1, Z1);
  {
    dim3 grid(3, MT);   // covers PHO=160
    mfma_gcn<KP1,KP2><<<grid, 256, 0, stream>>>(Z1, Bt1, H1h,
                                                gc1_b, bn3_g, bn3_b, NNODES, GC1_F);
  }

  // ---- GCN layer 2: Z2 = agg(H1h); AEh = tanh(bn4(Z2@W2 + b2)) ----
  gather_h<20,KP2><<<GGB, 256, 0, stream>>>(H1h, rowptr, adj, arel, alpha2, Z2);
  {
    dim3 grid(4, MT);   // covers PHO=224
    mfma_gcn<KP2,KPP><<<grid, 256, 0, stream>>>(Z2, Bt2, AEh,
                                                gc2_b, bn4_g, bn4_b, NNODES, D_F);
  }

  // ---- conv head (convout emitted as bf16 fc A-operand) ----
  build_s_k<<<BB, 256, 0, stream>>>(e1, rel, AEh, embrel, bn0_g, bn0_b, sbuf);
  {
    dim3 grid(CCH/8, BB);
    conv_bn_relu_k<<<grid, 256, 0, stream>>>(sbuf, conv_w, conv_b, bn1_g, bn1_b, convout);
  }
  // fc_w [200 x 40000] row-major == Bt layout; cast to bf16 (emb_h region dead)
  hipMemsetAsync(fcBt + (size_t)200*FCK, 0, (size_t)56*FCK*2, stream);
  {
    long n4 = (long)D_F*FCK/4;   // 2,000,000
    f32_to_bf16_flat_k<<<(int)((n4 + 255)/256), 256, 0, stream>>>(
        (const float4*)fc_w, fcBt, n4);
  }
  // fc: 128 x 200 = convout[128 x 40000] @ fcBt^T, split-K z=50, atomic fp32
  {
    dim3 grid(4, 2, 50);
    mfma_fc_k<<<grid, 256, 0, stream>>>(convout, fcBt, x2raw, BB, D_F, FCK/50);
  }
  fc_fin_k<<<(BB*D_F+255)/256, 256, 0, stream>>>(x2raw, fc_b, bn2_g, bn2_b, x2);

  // ---- NFM branch ----
  feats_k<<<BB, 256, 0, stream>>>(attr, AEh, ssum, deep);
  {
    dim3 grid((D_F+63)/64, (BB+63)/64, 1);
    gemm64<1,0,true><<<grid, 256, 0, stream>>>(deep, D_F, bi_w, D_F, nfm, D_F,
                                               bi_b, BB, D_F, D_F, D_F);
    gemm64<1,1,true><<<grid, 256, 0, stream>>>(ssum, D_F, si_w, D_F, nfm, D_F,
                                               si_b, BB, D_F, D_F, D_F);
    gemm64<0,0,true><<<grid, 256, 0, stream>>>(nfm, D_F, cs_w, 2*D_F, userb, D_F,
                                               nullptr, BB, D_F, D_F, D_F);
    gemm64<1,2,true><<<grid, 256, 0, stream>>>(x2, D_F, cs_w + D_F, 2*D_F, userb, D_F,
                                               cs_b, BB, D_F, D_F, D_F);
  }

  // ---- outputs ----
  conv_a_bf16_k<<<BB, 256, 0, stream>>>(userb, uh, D_F, KPP);
  {
    // pred = sigmoid(uh @ AEh^T) : M=128, N=100000, K=200(->224)
    dim3 grid(MT, 2);
    mfma_gemm<KPP,2><<<grid, 256, 0, stream>>>(uh, AEh, pred_out, NNODES, BB, NNODES);
  }
  {
    // clusters = sigmoid(userb @ fc2_w^T + fc2_b) : M=128, N=16, K=200 (fp32)
    dim3 grid(1, (BB+63)/64, 1);
    gemm64<2,0,true><<<grid, 256, 0, stream>>>(userb, D_F, fc2_w, D_F, clus_out, NCL,
                                               fc2_b, BB, NCL, D_F, D_F);
  }
}

// Round 6
// 812.973 us; speedup vs baseline: 1.9886x; 1.0495x over previous
//
#include <hip/hip_runtime.h>
#include <hip/hip_bf16.h>
#include <math.h>

// Problem constants (from reference setup_inputs)
#define NNODES 100000
#define INIT_F 100
#define GC1_F  150
#define D_F    200
#define CCH    200
#define BB     128
#define NA_    8
#define EDG    500000
#define NCL    16

#define MROWS  100032   // 1563 * 64, padded row count for MFMA A operands

// bf16 K-padded pitches (elements)
#define KP1    128      // layer1 input features: 100 -> 128
#define KP2    160      // layer2 input features: 150 -> 160
#define KPP    224      // head features: 200 -> 224
#define FCK    40000    // fc K

typedef __attribute__((ext_vector_type(8))) __bf16 bf16x8;
typedef __attribute__((ext_vector_type(4))) float  f32x4;

// ---------------- CSR build ----------------

__global__ void count_deg_k(const int* __restrict__ ei, int* __restrict__ deg, int E){
  int e = blockIdx.x*256 + threadIdx.x;
  if (e >= E) return;
  atomicAdd(&deg[ei[e]], 1);
  atomicAdd(&deg[ei[E+e]], 1);
}

__global__ void scan_block_k(const int* __restrict__ deg, int* __restrict__ incl,
                             int* __restrict__ bsum, int n){
  __shared__ int s[256];
  int t = threadIdx.x;
  int i = blockIdx.x*256 + t;
  int v = (i < n) ? deg[i] : 0;
  s[t] = v; __syncthreads();
  for (int off = 1; off < 256; off <<= 1){
    int x = (t >= off) ? s[t-off] : 0;
    __syncthreads();
    s[t] += x; __syncthreads();
  }
  if (i < n) incl[i] = s[t];
  if (t == 255) bsum[blockIdx.x] = s[255];
}

__global__ void scan_tot_k(const int* __restrict__ bsum, int* __restrict__ boff, int nb){
  __shared__ int s[512];
  int t = threadIdx.x;
  s[t] = (t < nb) ? bsum[t] : 0; __syncthreads();
  for (int off = 1; off < 512; off <<= 1){
    int x = (t >= off) ? s[t-off] : 0;
    __syncthreads();
    s[t] += x; __syncthreads();
  }
  if (t < nb) boff[t] = s[t] - bsum[t];   // exclusive block offset
}

__global__ void csr_fin_k(const int* __restrict__ incl, const int* __restrict__ deg,
                          const int* __restrict__ boff, int* __restrict__ rowptr,
                          int* __restrict__ cursor, int n, int total){
  int i = blockIdx.x*256 + threadIdx.x;
  if (i < n){
    int ex = incl[i] - deg[i] + boff[i >> 8];
    rowptr[i] = ex; cursor[i] = ex;
  }
  if (i == 0) rowptr[n] = total;
}

__global__ void fill_k(const int* __restrict__ ei, const int* __restrict__ erel,
                       int* __restrict__ cursor, int* __restrict__ adj,
                       int* __restrict__ arel, int E){
  int e = blockIdx.x*256 + threadIdx.x;
  if (e >= E) return;
  int r = ei[e], c = ei[E+e], rl = erel[e];
  int p = atomicAdd(&cursor[r], 1); adj[p] = c; arel[p] = rl;
  int q = atomicAdd(&cursor[c], 1); adj[q] = r; arel[q] = rl;
}

// ---------------- bf16 pre-GEMM gather, neighbor-parallel lane groups ----------------
// Z[v] = sum_j alpha[rel_j] * X[u_j].  One wave per node; G lane-groups of LPG
// lanes each process G neighbors concurrently (LPG*8 == PIN). Partials are
// reduced across groups with __shfl at the epilogue. Inactive/tail lanes use
// u=0,w=0 (row 0 is valid memory; weight 0 kills the contribution) so the row
// loads are never OOB and never exec-masked.

template<int G, int LPG, int PIN>
__global__ __launch_bounds__(256) void gather_g(
    const __bf16* __restrict__ X, const int* __restrict__ rowptr,
    const int* __restrict__ adj, const int* __restrict__ arel,
    const float* __restrict__ alpha, __bf16* __restrict__ Z)
{
  int wave = threadIdx.x >> 6;
  int lane = threadIdx.x & 63;
  int v = blockIdx.x*4 + wave;
  if (v >= NNODES) return;
  int grp = lane / LPG;          // group id (>=G means idle lane)
  int li  = lane - grp*LPG;      // lane within group
  bool act = grp < G;
  int s = rowptr[v], e = rowptr[v+1];
  float acc[8] = {};
  for (int jb = s; jb < e; jb += 2*G){
    int j0 = jb + grp, j1 = jb + grp + G;
    int u0 = 0, u1 = 0; float w0 = 0.f, w1 = 0.f;
    if (act && j0 < e){ u0 = adj[j0]; w0 = alpha[arel[j0]]; }
    if (act && j1 < e){ u1 = adj[j1]; w1 = alpha[arel[j1]]; }
    bf16x8 a = *(const bf16x8*)(X + (long)u0*PIN + li*8);
    bf16x8 b = *(const bf16x8*)(X + (long)u1*PIN + li*8);
    #pragma unroll
    for (int i = 0; i < 8; i++)
      acc[i] += w0*(float)a[i] + w1*(float)b[i];
  }
  // cross-group reduction: lanes [0,LPG) collect partials from groups 1..G-1
  #pragma unroll
  for (int g = 1; g < G; g++){
    #pragma unroll
    for (int i = 0; i < 8; i++)
      acc[i] += __shfl(acc[i], lane + g*LPG, 64);
  }
  if (lane < LPG){
    bf16x8 o;
    #pragma unroll
    for (int i = 0; i < 8; i++) o[i] = (__bf16)acc[i];
    *(bf16x8*)(Z + (long)v*PIN + lane*8) = o;
  }
}

// ---------------- GCN MFMA GEMM with fused bias+bn+tanh, bf16 out ----------------
// C[M x PHO](bf16) = tanh(bn(Z[M x KP] @ W + gb)); pad cols [N,PHO) written 0.
// A/B operand: lane l -> free idx = l&15, k = (l>>4)*8 + j ;  C/D: col=l&15, row=(l>>4)*4+reg

template<int KP, int PHO>
__global__ __launch_bounds__(256) void mfma_gcn(
    const __bf16* __restrict__ A, const __bf16* __restrict__ Bt,
    __bf16* __restrict__ C,
    const float* __restrict__ gb, const float* __restrict__ bng,
    const float* __restrict__ bnb, int M, int N)
{
  int w = threadIdx.x >> 6, l = threadIdx.x & 63;
  int m0 = blockIdx.y*64 + w*16;
  int n0 = blockIdx.x*64;
  int ml = l & 15, kq = l >> 4;
  const __bf16* Ap = A  + (long)(m0 + ml)*KP + kq*8;
  const __bf16* Bp = Bt + (long)(n0 + ml)*KP + kq*8;
  f32x4 acc[4] = {};
  #pragma unroll
  for (int k0 = 0; k0 < KP; k0 += 32){
    bf16x8 a = *(const bf16x8*)(Ap + k0);
    #pragma unroll
    for (int t = 0; t < 4; t++){
      bf16x8 b = *(const bf16x8*)(Bp + (long)t*16*KP + k0);
      acc[t] = __builtin_amdgcn_mfma_f32_16x16x32_bf16(a, b, acc[t], 0, 0, 0);
    }
  }
  const float inv = rsqrtf(1.0f + 1e-5f);
  int mr = m0 + kq*4;
  #pragma unroll
  for (int t = 0; t < 4; t++){
    int gn = n0 + t*16 + ml;
    if (gn >= PHO) continue;
    bool real = gn < N;
    float gbb = real ? gb[gn] : 0.f;
    float sc  = real ? bng[gn]*inv : 0.f;
    float bb_ = real ? bnb[gn] : 0.f;
    #pragma unroll
    for (int r = 0; r < 4; r++){
      int gm = mr + r;
      if (gm < M){
        float x = real ? tanhf((acc[t][r] + gbb)*sc + bb_) : 0.f;
        C[(long)gm*PHO + gn] = (__bf16)x;
      }
    }
  }
}

// ---------------- bf16 MFMA GEMM, fp32 out (pred) ----------------

template<int KP, int ACT>
__global__ __launch_bounds__(256) void mfma_gemm(
    const __bf16* __restrict__ A, const __bf16* __restrict__ Bt,
    float* __restrict__ C, long ldc, int M, int N)
{
  int w = threadIdx.x >> 6, l = threadIdx.x & 63;
  int m0 = blockIdx.y*64 + w*16;
  int n0 = blockIdx.x*64;
  int ml = l & 15, kq = l >> 4;
  const __bf16* Ap = A  + (long)(m0 + ml)*KP + kq*8;
  const __bf16* Bp = Bt + (long)(n0 + ml)*KP + kq*8;
  f32x4 acc[4] = {};
  #pragma unroll
  for (int k0 = 0; k0 < KP; k0 += 32){
    bf16x8 a = *(const bf16x8*)(Ap + k0);
    #pragma unroll
    for (int t = 0; t < 4; t++){
      bf16x8 b = *(const bf16x8*)(Bp + (long)t*16*KP + k0);
      acc[t] = __builtin_amdgcn_mfma_f32_16x16x32_bf16(a, b, acc[t], 0, 0, 0);
    }
  }
  int mr = m0 + kq*4;
  #pragma unroll
  for (int t = 0; t < 4; t++){
    int gn = n0 + t*16 + ml;
    if (gn >= N) continue;
    #pragma unroll
    for (int r = 0; r < 4; r++){
      int gm = mr + r;
      if (gm < M){
        float x = acc[t][r];
        if (ACT == 2) x = 1.f/(1.f + __expf(-x));
        C[(long)gm*ldc + gn] = x;
      }
    }
  }
}

// ---------------- fc MFMA: split-K, atomic accumulate ----------------

__global__ __launch_bounds__(256) void mfma_fc_k(
    const __bf16* __restrict__ A, const __bf16* __restrict__ Bt,
    float* __restrict__ C, int M, int N, int klen)
{
  int w = threadIdx.x >> 6, l = threadIdx.x & 63;
  int m0 = blockIdx.y*64 + w*16;
  int n0 = blockIdx.x*64;
  long kb = (long)blockIdx.z * klen;
  int ml = l & 15, kq = l >> 4;
  const __bf16* Ap = A  + (long)(m0 + ml)*FCK + kb + kq*8;
  const __bf16* Bp = Bt + (long)(n0 + ml)*FCK + kb + kq*8;
  f32x4 acc[4] = {};
  #pragma unroll 2
  for (int k0 = 0; k0 < klen; k0 += 32){
    bf16x8 a = *(const bf16x8*)(Ap + k0);
    #pragma unroll
    for (int t = 0; t < 4; t++){
      bf16x8 b = *(const bf16x8*)(Bp + (long)t*16*FCK + k0);
      acc[t] = __builtin_amdgcn_mfma_f32_16x16x32_bf16(a, b, acc[t], 0, 0, 0);
    }
  }
  int mr = m0 + kq*4;
  #pragma unroll
  for (int t = 0; t < 4; t++){
    int gn = n0 + t*16 + ml;
    if (gn >= N) continue;
    #pragma unroll
    for (int r = 0; r < 4; r++){
      int gm = mr + r;
      if (gm < M) atomicAdd(&C[(long)gm*N + gn], acc[t][r]);
    }
  }
}

// ---------------- conversion helpers ----------------

__global__ void conv_a_bf16_k(const float* __restrict__ src, __bf16* __restrict__ dst,
                              int cols, int colsP){
  long r = blockIdx.x;
  for (int j = threadIdx.x; j < colsP; j += blockDim.x)
    dst[r*colsP + j] = (j < cols) ? (__bf16)src[r*cols + j] : (__bf16)0.f;
}

__global__ void transpose_w_k(const float* __restrict__ W, __bf16* __restrict__ Bt,
                              int K, int N, int Kp){
  int n = blockIdx.x;
  for (int k = threadIdx.x; k < Kp; k += blockDim.x){
    float v = (k < K && n < N) ? W[(long)k*N + n] : 0.f;
    Bt[(long)n*Kp + k] = (__bf16)v;
  }
}

__global__ void f32_to_bf16_flat_k(const float4* __restrict__ src,
                                   __bf16* __restrict__ dst, long n4){
  long i = (long)blockIdx.x*256 + threadIdx.x;
  if (i >= n4) return;
  float4 v = src[i];
  __bf16 o[4] __attribute__((aligned(8))) =
      {(__bf16)v.x, (__bf16)v.y, (__bf16)v.z, (__bf16)v.w};
  *reinterpret_cast<uint2*>(dst + i*4) = *reinterpret_cast<const uint2*>(o);
}

// ---------------- small fused kernels ----------------

__global__ void build_s_k(const int* __restrict__ e1, const int* __restrict__ rel,
                          const __bf16* __restrict__ AEh, const float* __restrict__ embrel,
                          const float* __restrict__ g0, const float* __restrict__ b0,
                          float* __restrict__ s){
  int b = blockIdx.x, t = threadIdx.x;
  if (t >= D_F) return;
  const float inv = rsqrtf(1.0f + 1e-5f);
  float ev = (float)AEh[(long)e1[b]*KPP + t];
  s[(b*2+0)*D_F + t] = ev * (g0[0]*inv) + b0[0];
  s[(b*2+1)*D_F + t] = embrel[(long)rel[b]*D_F + t] * (g0[1]*inv) + b0[1];
}

__global__ void conv_bn_relu_k(const float* __restrict__ s, const float* __restrict__ cw,
                               const float* __restrict__ cb, const float* __restrict__ g1,
                               const float* __restrict__ b1, __bf16* __restrict__ out){
  __shared__ float sh[2][D_F];
  int b = blockIdx.y, c0 = blockIdx.x*8, t = threadIdx.x;
  if (t < D_F){
    sh[0][t] = s[(b*2+0)*D_F + t];
    sh[1][t] = s[(b*2+1)*D_F + t];
  }
  __syncthreads();
  if (t >= D_F) return;
  const float inv = rsqrtf(1.0f + 1e-5f);
  for (int cc = 0; cc < 8; cc++){
    int c = c0 + cc;
    float sum = cb[c];
    #pragma unroll
    for (int i = 0; i < 2; i++){
      #pragma unroll
      for (int k = 0; k < 5; k++){
        int h = t + k - 2;
        float sv = (h >= 0 && h < D_F) ? sh[i][h] : 0.f;
        sum += sv * cw[(c*2+i)*5 + k];
      }
    }
    float x = sum * (g1[c]*inv) + b1[c];
    out[((long)b*CCH + c)*D_F + t] = (__bf16)fmaxf(x, 0.f);
  }
}

__global__ void fc_fin_k(const float* __restrict__ raw, const float* __restrict__ fb,
                         const float* __restrict__ g, const float* __restrict__ bb,
                         float* __restrict__ x2){
  int i = blockIdx.x*256 + threadIdx.x;
  if (i >= BB*D_F) return;
  int j = i % D_F;
  const float inv = rsqrtf(1.0f + 1e-5f);
  float x = (raw[i] + fb[j]) * (g[j]*inv) + bb[j];
  x2[i] = fmaxf(x, 0.f);
}

__global__ void feats_k(const int* __restrict__ attr, const __bf16* __restrict__ AEh,
                        float* __restrict__ ssum, float* __restrict__ deep){
  int b = blockIdx.x, t = threadIdx.x;
  if (t >= D_F) return;
  float s = 0.f, sq = 0.f;
  #pragma unroll
  for (int a = 0; a < NA_; a++){
    int id = attr[b*NA_ + a];
    float v = (float)AEh[(long)id*KPP + t];
    s += v; sq += v*v;
  }
  ssum[b*D_F + t] = s;
  deep[b*D_F + t] = 0.5f*(s*s - sq);
}

// ---------------- generic 64x64 tiled fp32 GEMM (small shapes only) ----------------

template<int ACT, int MODE, bool BT>
__global__ __launch_bounds__(256) void gemm64(
    const float* __restrict__ A, int lda,
    const float* __restrict__ Bm, int ldb,
    float* __restrict__ Cm, int ldc,
    const float* __restrict__ bias,
    int M, int N, int K, int klen)
{
  __shared__ float As[16][68];
  __shared__ float Bs[16][68];
  int tid = threadIdx.x;
  int tm = tid >> 4, tn = tid & 15;
  int m0 = blockIdx.y*64, n0 = blockIdx.x*64;
  int k0 = blockIdx.z * klen;
  int kend = min(k0 + klen, K);
  float acc[4][4] = {};

  for (int ks = k0; ks < kend; ks += 16){
    #pragma unroll
    for (int i = 0; i < 4; i++){
      int idx = tid + 256*i;
      int m = idx & 63, k = idx >> 6;
      int gm = m0 + m, gk = ks + k;
      As[k][m] = (gm < M && gk < kend) ? A[(long)gm*lda + gk] : 0.f;
    }
    #pragma unroll
    for (int i = 0; i < 4; i++){
      int idx = tid + 256*i;
      int n = idx & 63, k = idx >> 6;
      int gn = n0 + n, gk = ks + k;
      float v = 0.f;
      if (gn < N && gk < kend)
        v = BT ? Bm[(long)gn*ldb + gk] : Bm[(long)gk*ldb + gn];
      Bs[k][n] = v;
    }
    __syncthreads();
    #pragma unroll
    for (int kk = 0; kk < 16; kk++){
      float a[4], b[4];
      #pragma unroll
      for (int i = 0; i < 4; i++) a[i] = As[kk][tm*4+i];
      #pragma unroll
      for (int i = 0; i < 4; i++) b[i] = Bs[kk][tn*4+i];
      #pragma unroll
      for (int i = 0; i < 4; i++)
        #pragma unroll
        for (int j = 0; j < 4; j++)
          acc[i][j] += a[i]*b[j];
    }
    __syncthreads();
  }

  #pragma unroll
  for (int i = 0; i < 4; i++){
    int gm = m0 + tm*4 + i; if (gm >= M) continue;
    #pragma unroll
    for (int j = 0; j < 4; j++){
      int gn = n0 + tn*4 + j; if (gn >= N) continue;
      long co = (long)gm*ldc + gn;
      float x = acc[i][j];
      if (MODE == 3){ atomicAdd(&Cm[co], x); continue; }
      if (MODE == 2) x += Cm[co];
      if (bias) x += bias[gn];
      if (ACT == 1) x = (x >= 0.f) ? x : 0.01f*x;
      else if (ACT == 2) x = 1.f/(1.f + __expf(-x));
      float r = x;
      if (MODE == 1) r = Cm[co] + x;
      Cm[co] = r;
    }
  }
}

// ---------------- launch ----------------

extern "C" void kernel_launch(void* const* d_in, const int* in_sizes, int n_in,
                              void* d_out, int out_size, void* d_ws, size_t ws_size,
                              hipStream_t stream) {
  const int* e1       = (const int*)d_in[0];
  const int* rel      = (const int*)d_in[1];
  const int* attr     = (const int*)d_in[2];
  const int* ei       = (const int*)d_in[4];
  const int* erel     = (const int*)d_in[5];
  const float* emb_e  = (const float*)d_in[6];
  const float* embrel = (const float*)d_in[7];
  const float* alpha1 = (const float*)d_in[8];
  const float* alpha2 = (const float*)d_in[9];
  const float* gc1_W  = (const float*)d_in[10];
  const float* gc1_b  = (const float*)d_in[11];
  const float* gc2_W  = (const float*)d_in[12];
  const float* gc2_b  = (const float*)d_in[13];
  const float* bn3_g  = (const float*)d_in[14];
  const float* bn3_b  = (const float*)d_in[15];
  const float* bn4_g  = (const float*)d_in[16];
  const float* bn4_b  = (const float*)d_in[17];
  const float* bn0_g  = (const float*)d_in[18];
  const float* bn0_b  = (const float*)d_in[19];
  const float* conv_w = (const float*)d_in[20];
  const float* conv_b = (const float*)d_in[21];
  const float* bn1_g  = (const float*)d_in[22];
  const float* bn1_b  = (const float*)d_in[23];
  const float* fc_w   = (const float*)d_in[24];
  const float* fc_b   = (const float*)d_in[25];
  const float* bn2_g  = (const float*)d_in[26];
  const float* bn2_b  = (const float*)d_in[27];
  const float* bi_w   = (const float*)d_in[28];
  const float* bi_b   = (const float*)d_in[29];
  const float* si_w   = (const float*)d_in[30];
  const float* si_b   = (const float*)d_in[31];
  const float* cs_w   = (const float*)d_in[32];
  const float* cs_b   = (const float*)d_in[33];
  const float* fc2_w  = (const float*)d_in[34];
  const float* fc2_b  = (const float*)d_in[35];

  float* pred_out = (float*)d_out;                       // 128 x 100000
  float* clus_out = (float*)d_out + (long)BB*NNODES;     // 128 x 16

  char* w = (char*)d_ws;
  size_t off = 0;
  auto alloc = [&](size_t bytes) -> void* {
    off = (off + 255) & ~(size_t)255;
    void* p = w + off;
    off += bytes;
    return p;
  };
  __bf16* AEh  = (__bf16*)alloc((size_t)MROWS*KPP*2);   // 44.8 MB, final embeddings
  void* bufA   = alloc((size_t)MROWS*KP1*2);            // emb_h, later fcBt (20.5MB<25.6MB)
  void* bufB   = alloc((size_t)MROWS*KP1*2);            // Z1, later convout (10.3MB<25.6MB)
  __bf16* H1h  = (__bf16*)alloc((size_t)MROWS*KP2*2);   // 32 MB
  __bf16* Z2   = (__bf16*)alloc((size_t)MROWS*KP2*2);   // 32 MB

  int* deg    = (int*)alloc((size_t)NNODES*4);
  int* incl   = (int*)alloc((size_t)NNODES*4);
  int* bsum   = (int*)alloc(512*4);
  int* boff   = (int*)alloc(512*4);
  int* rowptr = (int*)alloc((size_t)(NNODES+1)*4);
  int* cursor = (int*)alloc((size_t)NNODES*4);
  int* adj    = (int*)alloc((size_t)2*EDG*4);
  int* arel   = (int*)alloc((size_t)2*EDG*4);
  __bf16* Bt1 = (__bf16*)alloc((size_t)192*KP1*2);
  __bf16* Bt2 = (__bf16*)alloc((size_t)256*KP2*2);
  __bf16* uh  = (__bf16*)alloc((size_t)BB*KPP*2);
  float* sbuf   = (float*)alloc((size_t)BB*2*D_F*4);
  float* x2raw  = (float*)alloc((size_t)BB*D_F*4);
  float* x2     = (float*)alloc((size_t)BB*D_F*4);
  float* ssum   = (float*)alloc((size_t)BB*D_F*4);
  float* deep   = (float*)alloc((size_t)BB*D_F*4);
  float* nfm    = (float*)alloc((size_t)BB*D_F*4);
  float* userb  = (float*)alloc((size_t)BB*D_F*4);

  __bf16* emb_h   = (__bf16*)bufA;   // pitch 128
  __bf16* fcBt    = (__bf16*)bufA;   // 256 x 40000 (emb_h dead after gather1)
  __bf16* Z1      = (__bf16*)bufB;   // pitch 128
  __bf16* convout = (__bf16*)bufB;   // 128 x 40000 (Z1 dead after GEMM1)

  const int EB = (EDG + 255)/256;
  const int NB = (NNODES + 255)/256;
  const int GGB = (NNODES + 3)/4;
  const int MT = MROWS/64;        // 1563

  // ---- CSR build ----
  hipMemsetAsync(deg, 0, (size_t)NNODES*4, stream);
  hipMemsetAsync(x2raw, 0, (size_t)BB*D_F*4, stream);
  count_deg_k<<<EB, 256, 0, stream>>>(ei, deg, EDG);
  scan_block_k<<<NB, 256, 0, stream>>>(deg, incl, bsum, NNODES);
  scan_tot_k<<<1, 512, 0, stream>>>(bsum, boff, NB);
  csr_fin_k<<<NB, 256, 0, stream>>>(incl, deg, boff, rowptr, cursor, NNODES, 2*EDG);
  fill_k<<<EB, 256, 0, stream>>>(ei, erel, cursor, adj, arel, EDG);

  // ---- operand prep ----
  conv_a_bf16_k<<<NNODES, 128, 0, stream>>>(emb_e, emb_h, INIT_F, KP1);
  transpose_w_k<<<192, 128, 0, stream>>>(gc1_W, Bt1, INIT_F, GC1_F, KP1);
  transpose_w_k<<<256, 128, 0, stream>>>(gc2_W, Bt2, GC1_F, D_F, KP2);

  // ---- GCN layer 1: Z1 = agg(emb_h); H1h = tanh(bn3(Z1@W1 + b1)) ----
  gather_g<4,16,KP1><<<GGB, 256, 0, stream>>>(emb_h, rowptr, adj, arel, alpha1, Z1);
  {
    dim3 grid(3, MT);   // covers PHO=160
    mfma_gcn<KP1,KP2><<<grid, 256, 0, stream>>>(Z1, Bt1, H1h,
                                                gc1_b, bn3_g, bn3_b, NNODES, GC1_F);
  }

  // ---- GCN layer 2: Z2 = agg(H1h); AEh = tanh(bn4(Z2@W2 + b2)) ----
  gather_g<3,20,KP2><<<GGB, 256, 0, stream>>>(H1h, rowptr, adj, arel, alpha2, Z2);
  {
    dim3 grid(4, MT);   // covers PHO=224
    mfma_gcn<KP2,KPP><<<grid, 256, 0, stream>>>(Z2, Bt2, AEh,
                                                gc2_b, bn4_g, bn4_b, NNODES, D_F);
  }

  // ---- conv head (convout emitted as bf16 fc A-operand) ----
  build_s_k<<<BB, 256, 0, stream>>>(e1, rel, AEh, embrel, bn0_g, bn0_b, sbuf);
  {
    dim3 grid(CCH/8, BB);
    conv_bn_relu_k<<<grid, 256, 0, stream>>>(sbuf, conv_w, conv_b, bn1_g, bn1_b, convout);
  }
  // fc_w [200 x 40000] row-major == Bt layout; cast to bf16 (emb_h region dead)
  hipMemsetAsync(fcBt + (size_t)200*FCK, 0, (size_t)56*FCK*2, stream);
  {
    long n4 = (long)D_F*FCK/4;   // 2,000,000
    f32_to_bf16_flat_k<<<(int)((n4 + 255)/256), 256, 0, stream>>>(
        (const float4*)fc_w, fcBt, n4);
  }
  // fc: 128 x 200 = convout[128 x 40000] @ fcBt^T, split-K z=50, atomic fp32
  {
    dim3 grid(4, 2, 50);
    mfma_fc_k<<<grid, 256, 0, stream>>>(convout, fcBt, x2raw, BB, D_F, FCK/50);
  }
  fc_fin_k<<<(BB*D_F+255)/256, 256, 0, stream>>>(x2raw, fc_b, bn2_g, bn2_b, x2);

  // ---- NFM branch ----
  feats_k<<<BB, 256, 0, stream>>>(attr, AEh, ssum, deep);
  {
    dim3 grid((D_F+63)/64, (BB+63)/64, 1);
    gemm64<1,0,true><<<grid, 256, 0, stream>>>(deep, D_F, bi_w, D_F, nfm, D_F,
                                               bi_b, BB, D_F, D_F, D_F);
    gemm64<1,1,true><<<grid, 256, 0, stream>>>(ssum, D_F, si_w, D_F, nfm, D_F,
                                               si_b, BB, D_F, D_F, D_F);
    gemm64<0,0,true><<<grid, 256, 0, stream>>>(nfm, D_F, cs_w, 2*D_F, userb, D_F,
                                               nullptr, BB, D_F, D_F, D_F);
    gemm64<1,2,true><<<grid, 256, 0, stream>>>(x2, D_F, cs_w + D_F, 2*D_F, userb, D_F,
                                               cs_b, BB, D_F, D_F, D_F);
  }

  // ---- outputs ----
  conv_a_bf16_k<<<BB, 256, 0, stream>>>(userb, uh, D_F, KPP);
  {
    // pred = sigmoid(uh @ AEh^T) : M=128, N=100000, K=200(->224)
    dim3 grid(MT, 2);
    mfma_gemm<KPP,2><<<grid, 256, 0, stream>>>(uh, AEh, pred_out, NNODES, BB, NNODES);
  }
  {
    // clusters = sigmoid(userb @ fc2_w^T + fc2_b) : M=128, N=16, K=200 (fp32)
    dim3 grid(1, (BB+63)/64, 1);
    gemm64<2,0,true><<<grid, 256, 0, stream>>>(userb, D_F, fc2_w, D_F, clus_out, NCL,
                                               fc2_b, BB, NCL, D_F, D_F);
  }
}